// Round 1
// baseline (1727.015 us; speedup 1.0000x reference)
//
#include <hip/hip_runtime.h>
#include <cstdint>
#include <cstddef>

#define N_USERS   100000
#define N_NODES   500000
#define DIM       64
#define N_EDGES   2000000
#define BATCH     4096

// ---------------- degree count (into float buffer, pre-zeroed) --------------
__global__ void k_deg(const int* __restrict__ dst, float* __restrict__ deg) {
    int e = blockIdx.x * blockDim.x + threadIdx.x;
    if (e < N_EDGES) atomicAdd(&deg[dst[e]], 1.0f);
}

// ---------------- deg -> dinv in place --------------------------------------
__global__ void k_dinv(float* __restrict__ deg) {
    int i = blockIdx.x * blockDim.x + threadIdx.x;
    if (i < N_NODES) {
        float d = deg[i];
        deg[i] = (d > 0.0f) ? rsqrtf(d) : 0.0f;
    }
}

// ---------------- one propagation layer: xout += A_norm * xin ---------------
// one wave per edge (lane = dim), grid-stride over edges
__global__ void k_prop(const int* __restrict__ src, const int* __restrict__ dst,
                       const float* __restrict__ dinv,
                       const float* __restrict__ xin, float* __restrict__ xout) {
    int lane = threadIdx.x & 63;
    int wave = (blockIdx.x * blockDim.x + threadIdx.x) >> 6;
    int nwaves = (gridDim.x * blockDim.x) >> 6;
    for (int e = wave; e < N_EDGES; e += nwaves) {
        int s = src[e];
        int t = dst[e];
        float nrm = dinv[s] * dinv[t];
        if (nrm != 0.0f) {
            float v = xin[(size_t)s * DIM + lane] * nrm;
            atomicAdd(&xout[(size_t)t * DIM + lane], v);
        }
    }
}

// ---------------- init batch accumulator with emb rows ----------------------
__global__ void k_gather_init(const float* __restrict__ emb,
                              const int* __restrict__ u, const int* __restrict__ p,
                              const int* __restrict__ n, float* __restrict__ acc) {
    int lane = threadIdx.x & 63;
    int w = (blockIdx.x * blockDim.x + threadIdx.x) >> 6;
    if (w >= 3 * BATCH) return;
    int idx;
    if (w < BATCH)            idx = u[w];
    else if (w < 2 * BATCH)   idx = p[w - BATCH];
    else                      idx = n[w - 2 * BATCH];
    acc[(size_t)w * DIM + lane] = emb[(size_t)idx * DIM + lane];
}

// ---------------- acc += x[idx] for the batch rows --------------------------
__global__ void k_gather_acc(const float* __restrict__ x,
                             const int* __restrict__ u, const int* __restrict__ p,
                             const int* __restrict__ n, float* __restrict__ acc) {
    int lane = threadIdx.x & 63;
    int w = (blockIdx.x * blockDim.x + threadIdx.x) >> 6;
    if (w >= 3 * BATCH) return;
    int idx;
    if (w < BATCH)            idx = u[w];
    else if (w < 2 * BATCH)   idx = p[w - BATCH];
    else                      idx = n[w - 2 * BATCH];
    acc[(size_t)w * DIM + lane] += x[(size_t)idx * DIM + lane];
}

// ---------------- final loss: dot products + softplus + L2 reg --------------
__global__ void k_loss(const float* __restrict__ acc, const float* __restrict__ emb,
                       const int* __restrict__ u, const int* __restrict__ p,
                       const int* __restrict__ n, float* __restrict__ out) {
    int lane = threadIdx.x & 63;
    int w = (blockIdx.x * blockDim.x + threadIdx.x) >> 6;
    if (w >= BATCH) return;
    const float quarter = 0.25f;  // mean over (layers+1)=4 stacked embeddings
    float ud = acc[(size_t)w * DIM + lane] * quarter;
    float pd = acc[(size_t)(BATCH + w) * DIM + lane] * quarter;
    float nd = acc[(size_t)(2 * BATCH + w) * DIM + lane] * quarter;
    float pos = ud * pd;
    float neg = ud * nd;
    int ui = u[w], pi = p[w], ni = n[w];
    float ue = emb[(size_t)ui * DIM + lane];
    float pe = emb[(size_t)pi * DIM + lane];
    float ne = emb[(size_t)ni * DIM + lane];
    float sq = ue * ue + pe * pe + ne * ne;
    // wave-wide reductions (64 lanes)
    for (int off = 32; off; off >>= 1) {
        pos += __shfl_xor(pos, off, 64);
        neg += __shfl_xor(neg, off, 64);
        sq  += __shfl_xor(sq,  off, 64);
    }
    if (lane == 0) {
        float z = neg - pos;
        // stable softplus
        float sp = fmaxf(z, 0.0f) + log1pf(expf(-fabsf(z)));
        float contrib = sp * (1.0f / BATCH) + 1e-4f * 0.5f * sq * (1.0f / BATCH);
        atomicAdd(out, contrib);
    }
}

extern "C" void kernel_launch(void* const* d_in, const int* in_sizes, int n_in,
                              void* d_out, int out_size, void* d_ws, size_t ws_size,
                              hipStream_t stream) {
    const float* emb  = (const float*)d_in[0];
    const int*   edge = (const int*)d_in[1];
    const int*   src  = edge;             // edge_index[0]
    const int*   dst  = edge + N_EDGES;   // edge_index[1]
    const int*   uidx = (const int*)d_in[2];
    const int*   pidx = (const int*)d_in[3];
    const int*   nidx = (const int*)d_in[4];
    float* out = (float*)d_out;

    // workspace layout
    float* xbuf0 = (float*)d_ws;                        // N_NODES*DIM
    float* xbuf1 = xbuf0 + (size_t)N_NODES * DIM;       // N_NODES*DIM
    float* dinv  = xbuf1 + (size_t)N_NODES * DIM;       // N_NODES (deg then dinv)
    float* acc   = dinv + N_NODES;                      // 3*BATCH*DIM

    const size_t xbytes = (size_t)N_NODES * DIM * sizeof(float);

    hipMemsetAsync(dinv, 0, (size_t)N_NODES * sizeof(float), stream);
    hipMemsetAsync(out, 0, sizeof(float), stream);

    k_deg<<<(N_EDGES + 255) / 256, 256, 0, stream>>>(dst, dinv);
    k_dinv<<<(N_NODES + 255) / 256, 256, 0, stream>>>(dinv);
    k_gather_init<<<(3 * BATCH * 64 + 255) / 256, 256, 0, stream>>>(emb, uidx, pidx, nidx, acc);

    const int PROP_BLOCKS = 8192;  // grid-stride, 4 waves/block

    // layer 1: emb -> xbuf0
    hipMemsetAsync(xbuf0, 0, xbytes, stream);
    k_prop<<<PROP_BLOCKS, 256, 0, stream>>>(src, dst, dinv, emb, xbuf0);
    k_gather_acc<<<(3 * BATCH * 64 + 255) / 256, 256, 0, stream>>>(xbuf0, uidx, pidx, nidx, acc);

    // layer 2: xbuf0 -> xbuf1
    hipMemsetAsync(xbuf1, 0, xbytes, stream);
    k_prop<<<PROP_BLOCKS, 256, 0, stream>>>(src, dst, dinv, xbuf0, xbuf1);
    k_gather_acc<<<(3 * BATCH * 64 + 255) / 256, 256, 0, stream>>>(xbuf1, uidx, pidx, nidx, acc);

    // layer 3: xbuf1 -> xbuf0
    hipMemsetAsync(xbuf0, 0, xbytes, stream);
    k_prop<<<PROP_BLOCKS, 256, 0, stream>>>(src, dst, dinv, xbuf1, xbuf0);
    k_gather_acc<<<(3 * BATCH * 64 + 255) / 256, 256, 0, stream>>>(xbuf0, uidx, pidx, nidx, acc);

    k_loss<<<(BATCH * 64 + 255) / 256, 256, 0, stream>>>(acc, emb, uidx, pidx, nidx, out);
}

// Round 2
// 1310.199 us; speedup vs baseline: 1.3181x; 1.3181x over previous
//
#include <hip/hip_runtime.h>
#include <cstdint>
#include <cstddef>

#define N_USERS   100000
#define N_NODES   500000
#define DIM       64
#define N_EDGES   2000000
#define BATCH     4096
#define SCAN_B    1024
#define NBLK      ((N_NODES + SCAN_B - 1) / SCAN_B)   // 489
#define X1C_CAP   350000   // compact x1 rows; expected distinct setB ~205k

// ---------------- degree histogram (int) ------------------------------------
__global__ void k_deg(const int* __restrict__ dst, int* __restrict__ deg) {
    int e = blockIdx.x * blockDim.x + threadIdx.x;
    if (e < N_EDGES) atomicAdd(&deg[dst[e]], 1);
}

// ---------------- scan stage 1: per-block sums ------------------------------
__global__ void k_scan1(const int* __restrict__ deg, int* __restrict__ bsum) {
    __shared__ int s[SCAN_B];
    int i = blockIdx.x * SCAN_B + threadIdx.x;
    s[threadIdx.x] = (i < N_NODES) ? deg[i] : 0;
    __syncthreads();
    for (int off = SCAN_B / 2; off; off >>= 1) {
        if (threadIdx.x < off) s[threadIdx.x] += s[threadIdx.x + off];
        __syncthreads();
    }
    if (threadIdx.x == 0) bsum[blockIdx.x] = s[0];
}

// ---------------- scan stage 2: exclusive scan of block sums ----------------
__global__ void k_scan2(const int* __restrict__ bsum, int* __restrict__ boff,
                        int* __restrict__ rowstart) {
    __shared__ int s[512];
    int v = (threadIdx.x < NBLK) ? bsum[threadIdx.x] : 0;
    s[threadIdx.x] = v;
    __syncthreads();
    for (int off = 1; off < 512; off <<= 1) {
        int t = (threadIdx.x >= off) ? s[threadIdx.x - off] : 0;
        __syncthreads();
        s[threadIdx.x] += t;
        __syncthreads();
    }
    if (threadIdx.x < NBLK) boff[threadIdx.x] = s[threadIdx.x] - v;  // exclusive
    if (threadIdx.x == 0) rowstart[N_NODES] = N_EDGES;
}

// ---------------- scan stage 3: per-element exclusive scan + offset ---------
__global__ void k_scan3(const int* __restrict__ deg, const int* __restrict__ boff,
                        int* __restrict__ rowstart, int* __restrict__ cursor) {
    __shared__ int s[SCAN_B];
    int i = blockIdx.x * SCAN_B + threadIdx.x;
    int v = (i < N_NODES) ? deg[i] : 0;
    s[threadIdx.x] = v;
    __syncthreads();
    for (int off = 1; off < SCAN_B; off <<= 1) {
        int t = (threadIdx.x >= off) ? s[threadIdx.x - off] : 0;
        __syncthreads();
        s[threadIdx.x] += t;
        __syncthreads();
    }
    if (i < N_NODES) {
        int ex = s[threadIdx.x] - v + boff[blockIdx.x];
        rowstart[i] = ex;
        cursor[i] = ex;
    }
}

// ---------------- scatter edges into CSR order ------------------------------
__global__ void k_scatter(const int* __restrict__ src, const int* __restrict__ dst,
                          int* __restrict__ cursor, int* __restrict__ csr_src) {
    int e = blockIdx.x * blockDim.x + threadIdx.x;
    if (e < N_EDGES) {
        int t = dst[e];
        int slot = atomicAdd(&cursor[t], 1);
        csr_src[slot] = src[e];
    }
}

// ---------------- deg -> dinv -----------------------------------------------
__global__ void k_dinv(const int* __restrict__ deg, float* __restrict__ dinv) {
    int i = blockIdx.x * blockDim.x + threadIdx.x;
    if (i < N_NODES) {
        int d = deg[i];
        dinv[i] = (d > 0) ? rsqrtf((float)d) : 0.0f;
    }
}

// ---------------- mark batch indices into a byte flag -----------------------
__global__ void k_mark_idx(const int* __restrict__ u, const int* __restrict__ p,
                           const int* __restrict__ n, unsigned char* __restrict__ f) {
    int i = blockIdx.x * blockDim.x + threadIdx.x;
    if (i >= 3 * BATCH) return;
    int idx;
    if (i < BATCH)          idx = u[i];
    else if (i < 2 * BATCH) idx = p[i - BATCH];
    else                    idx = n[i - 2 * BATCH];
    f[idx] = 1;
}

// ---------------- expand: fout |= N(fin) ------------------------------------
__global__ void k_expand_flag(const unsigned char* __restrict__ fin,
                              unsigned char* __restrict__ fout,
                              const int* __restrict__ rowstart,
                              const int* __restrict__ csr_src) {
    int t = blockIdx.x * blockDim.x + threadIdx.x;
    if (t >= N_NODES || !fin[t]) return;
    int b = rowstart[t], e = rowstart[t + 1];
    for (int i = b; i < e; ++i) fout[csr_src[i]] = 1;
}

// ---------------- claim compact slot in mapB --------------------------------
__device__ __forceinline__ void claim(int* mapB, int* counter, int s) {
    int old = atomicCAS(&mapB[s], -1, -2);
    if (old == -1) mapB[s] = atomicAdd(counter, 1);
}

__global__ void k_expand_map(const unsigned char* __restrict__ fin,
                             int* __restrict__ mapB, int* __restrict__ counter,
                             const int* __restrict__ rowstart,
                             const int* __restrict__ csr_src) {
    int t = blockIdx.x * blockDim.x + threadIdx.x;
    if (t >= N_NODES || !fin[t]) return;
    int b = rowstart[t], e = rowstart[t + 1];
    for (int i = b; i < e; ++i) claim(mapB, counter, csr_src[i]);
}

__global__ void k_markB_idx(const int* __restrict__ u, const int* __restrict__ p,
                            const int* __restrict__ n, int* __restrict__ mapB,
                            int* __restrict__ counter) {
    int i = blockIdx.x * blockDim.x + threadIdx.x;
    if (i >= 3 * BATCH) return;
    int idx;
    if (i < BATCH)          idx = u[i];
    else if (i < 2 * BATCH) idx = p[i - BATCH];
    else                    idx = n[i - 2 * BATCH];
    claim(mapB, counter, idx);
}

// ---------------- layer 1: emb -> x1c (compact, setB nodes) -----------------
__global__ void k_prop1(const float* __restrict__ emb, const int* __restrict__ mapB,
                        const float* __restrict__ dinv, const int* __restrict__ rowstart,
                        const int* __restrict__ csr_src, float* __restrict__ x1c) {
    int lane = threadIdx.x & 63;
    int w = (blockIdx.x * blockDim.x + threadIdx.x) >> 6;
    if (w >= N_NODES) return;
    int slot = mapB[w];
    if (slot < 0) return;
    float acc = 0.0f;
    int b = rowstart[w], e = rowstart[w + 1];
    for (int i = b; i < e; ++i) {
        int s = csr_src[i];
        acc += emb[(size_t)s * DIM + lane] * dinv[s];
    }
    x1c[(size_t)slot * DIM + lane] = acc * dinv[w];
}

// ---------------- layer 2: x1c -> x2 (full rows at setA nodes) --------------
__global__ void k_prop2(const float* __restrict__ x1c, const int* __restrict__ mapB,
                        const unsigned char* __restrict__ fA,
                        const float* __restrict__ dinv, const int* __restrict__ rowstart,
                        const int* __restrict__ csr_src, float* __restrict__ x2) {
    int lane = threadIdx.x & 63;
    int w = (blockIdx.x * blockDim.x + threadIdx.x) >> 6;
    if (w >= N_NODES) return;
    if (!fA[w]) return;
    float acc = 0.0f;
    int b = rowstart[w], e = rowstart[w + 1];
    for (int i = b; i < e; ++i) {
        int s = csr_src[i];
        acc += x1c[(size_t)mapB[s] * DIM + lane] * dinv[s];
    }
    x2[(size_t)w * DIM + lane] = acc * dinv[w];
}

// ---------------- layer 3: x2 -> x3c (compact, 3*BATCH rows) ----------------
__global__ void k_prop3(const float* __restrict__ x2,
                        const int* __restrict__ u, const int* __restrict__ p,
                        const int* __restrict__ n,
                        const float* __restrict__ dinv, const int* __restrict__ rowstart,
                        const int* __restrict__ csr_src, float* __restrict__ x3c) {
    int lane = threadIdx.x & 63;
    int w = (blockIdx.x * blockDim.x + threadIdx.x) >> 6;
    if (w >= 3 * BATCH) return;
    int t;
    if (w < BATCH)          t = u[w];
    else if (w < 2 * BATCH) t = p[w - BATCH];
    else                    t = n[w - 2 * BATCH];
    float acc = 0.0f;
    int b = rowstart[t], e = rowstart[t + 1];
    for (int i = b; i < e; ++i) {
        int s = csr_src[i];
        acc += x2[(size_t)s * DIM + lane] * dinv[s];
    }
    x3c[(size_t)w * DIM + lane] = acc * dinv[t];
}

// ---------------- final loss ------------------------------------------------
__global__ void k_loss(const float* __restrict__ emb, const float* __restrict__ x1c,
                       const float* __restrict__ x2, const float* __restrict__ x3c,
                       const int* __restrict__ mapB,
                       const int* __restrict__ u, const int* __restrict__ p,
                       const int* __restrict__ n, float* __restrict__ out) {
    int lane = threadIdx.x & 63;
    int w = (blockIdx.x * blockDim.x + threadIdx.x) >> 6;
    if (w >= BATCH) return;
    int ui = u[w], pi = p[w], ni = n[w];
    float ue = emb[(size_t)ui * DIM + lane];
    float pe = emb[(size_t)pi * DIM + lane];
    float ne = emb[(size_t)ni * DIM + lane];
    float uall = 0.25f * (ue + x1c[(size_t)mapB[ui] * DIM + lane]
                             + x2[(size_t)ui * DIM + lane]
                             + x3c[(size_t)w * DIM + lane]);
    float pall = 0.25f * (pe + x1c[(size_t)mapB[pi] * DIM + lane]
                             + x2[(size_t)pi * DIM + lane]
                             + x3c[(size_t)(BATCH + w) * DIM + lane]);
    float nall = 0.25f * (ne + x1c[(size_t)mapB[ni] * DIM + lane]
                             + x2[(size_t)ni * DIM + lane]
                             + x3c[(size_t)(2 * BATCH + w) * DIM + lane]);
    float pos = uall * pall;
    float neg = uall * nall;
    float sq  = ue * ue + pe * pe + ne * ne;
    for (int off = 32; off; off >>= 1) {
        pos += __shfl_xor(pos, off, 64);
        neg += __shfl_xor(neg, off, 64);
        sq  += __shfl_xor(sq,  off, 64);
    }
    if (lane == 0) {
        float z = neg - pos;
        float sp = fmaxf(z, 0.0f) + log1pf(expf(-fabsf(z)));
        float contrib = sp * (1.0f / BATCH) + 1e-4f * 0.5f * sq * (1.0f / BATCH);
        atomicAdd(out, contrib);
    }
}

extern "C" void kernel_launch(void* const* d_in, const int* in_sizes, int n_in,
                              void* d_out, int out_size, void* d_ws, size_t ws_size,
                              hipStream_t stream) {
    const float* emb  = (const float*)d_in[0];
    const int*   edge = (const int*)d_in[1];
    const int*   src  = edge;
    const int*   dst  = edge + N_EDGES;
    const int*   uidx = (const int*)d_in[2];
    const int*   pidx = (const int*)d_in[3];
    const int*   nidx = (const int*)d_in[4];
    float* out = (float*)d_out;

    // ---- workspace layout (all within known-safe ~261 MB) ----
    char* w = (char*)d_ws;
    float* x2       = (float*)w;                 w += (size_t)N_NODES * DIM * 4;   // 128.0 MB
    float* x1c      = (float*)w;                 w += (size_t)X1C_CAP * DIM * 4;   //  89.6 MB
    float* x3c      = (float*)w;                 w += (size_t)3 * BATCH * DIM * 4; //   3.1 MB
    float* dinv     = (float*)w;                 w += (size_t)N_NODES * 4;
    int*   deg      = (int*)w;                   w += (size_t)N_NODES * 4;
    int*   rowstart = (int*)w;                   w += (size_t)(N_NODES + 4) * 4;
    int*   cursor   = (int*)w;                   w += (size_t)N_NODES * 4;
    int*   csr_src  = (int*)w;                   w += (size_t)N_EDGES * 4;
    int*   mapB     = (int*)w;                   w += (size_t)N_NODES * 4;
    unsigned char* f3 = (unsigned char*)w;       w += N_NODES;
    unsigned char* fA = (unsigned char*)w;       w += N_NODES;
    int*   bsum     = (int*)w;                   w += (size_t)NBLK * 4;
    int*   boff     = (int*)w;                   w += (size_t)NBLK * 4;
    int*   counter  = (int*)w;                   w += 16;

    hipMemsetAsync(deg, 0, (size_t)N_NODES * 4, stream);
    hipMemsetAsync(mapB, 0xFF, (size_t)N_NODES * 4, stream);   // -1
    hipMemsetAsync(f3, 0, N_NODES, stream);
    hipMemsetAsync(fA, 0, N_NODES, stream);
    hipMemsetAsync(counter, 0, 4, stream);
    hipMemsetAsync(out, 0, 4, stream);

    // CSR build
    k_deg<<<(N_EDGES + 255) / 256, 256, 0, stream>>>(dst, deg);
    k_scan1<<<NBLK, SCAN_B, 0, stream>>>(deg, bsum);
    k_scan2<<<1, 512, 0, stream>>>(bsum, boff, rowstart);
    k_scan3<<<NBLK, SCAN_B, 0, stream>>>(deg, boff, rowstart, cursor);
    k_scatter<<<(N_EDGES + 255) / 256, 256, 0, stream>>>(src, dst, cursor, csr_src);
    k_dinv<<<(N_NODES + 255) / 256, 256, 0, stream>>>(deg, dinv);

    // frontier sets: f3 = batch; fA = f3 ∪ N(f3); mapB ~ fA-expanded ∪ batch
    k_mark_idx<<<(3 * BATCH + 255) / 256, 256, 0, stream>>>(uidx, pidx, nidx, f3);
    k_expand_flag<<<(N_NODES + 255) / 256, 256, 0, stream>>>(f3, fA, rowstart, csr_src);
    k_mark_idx<<<(3 * BATCH + 255) / 256, 256, 0, stream>>>(uidx, pidx, nidx, fA);
    k_expand_map<<<(N_NODES + 255) / 256, 256, 0, stream>>>(fA, mapB, counter, rowstart, csr_src);
    k_markB_idx<<<(3 * BATCH + 255) / 256, 256, 0, stream>>>(uidx, pidx, nidx, mapB, counter);

    // sparse propagation (pull-style over CSR, no float atomics)
    const int PROP_T = 256;
    k_prop1<<<(N_NODES * 64 + PROP_T - 1) / PROP_T, PROP_T, 0, stream>>>(
        emb, mapB, dinv, rowstart, csr_src, x1c);
    k_prop2<<<(N_NODES * 64 + PROP_T - 1) / PROP_T, PROP_T, 0, stream>>>(
        x1c, mapB, fA, dinv, rowstart, csr_src, x2);
    k_prop3<<<(3 * BATCH * 64 + PROP_T - 1) / PROP_T, PROP_T, 0, stream>>>(
        x2, uidx, pidx, nidx, dinv, rowstart, csr_src, x3c);

    k_loss<<<(BATCH * 64 + 255) / 256, 256, 0, stream>>>(
        emb, x1c, x2, x3c, mapB, uidx, pidx, nidx, out);
}

// Round 3
// 776.758 us; speedup vs baseline: 2.2234x; 1.6868x over previous
//
#include <hip/hip_runtime.h>
#include <cstdint>
#include <cstddef>

#define N_USERS   100000
#define N_NODES   500000
#define DIM       64
#define N_EDGES   2000000
#define BATCH     4096
#define SCAN_B    1024
#define NBLK      ((N_NODES + SCAN_B - 1) / SCAN_B)   // 489
#define X1C_CAP   350000   // compact x1 rows; expected |fB| ~220k

// ---------------- degree histogram (int) ------------------------------------
__global__ void k_deg(const int* __restrict__ dst, int* __restrict__ deg) {
    int e = blockIdx.x * blockDim.x + threadIdx.x;
    if (e < N_EDGES) atomicAdd(&deg[dst[e]], 1);
}

// ---------------- scan stage 1: per-block sums (int input) ------------------
__global__ void k_scan1(const int* __restrict__ v, int* __restrict__ bsum) {
    __shared__ int s[SCAN_B];
    int i = blockIdx.x * SCAN_B + threadIdx.x;
    s[threadIdx.x] = (i < N_NODES) ? v[i] : 0;
    __syncthreads();
    for (int off = SCAN_B / 2; off; off >>= 1) {
        if (threadIdx.x < off) s[threadIdx.x] += s[threadIdx.x + off];
        __syncthreads();
    }
    if (threadIdx.x == 0) bsum[blockIdx.x] = s[0];
}

// ---------------- scan stage 1b: per-block sums (byte input) ----------------
__global__ void k_scan1b(const unsigned char* __restrict__ v, int* __restrict__ bsum) {
    __shared__ int s[SCAN_B];
    int i = blockIdx.x * SCAN_B + threadIdx.x;
    s[threadIdx.x] = (i < N_NODES) ? (int)v[i] : 0;
    __syncthreads();
    for (int off = SCAN_B / 2; off; off >>= 1) {
        if (threadIdx.x < off) s[threadIdx.x] += s[threadIdx.x + off];
        __syncthreads();
    }
    if (threadIdx.x == 0) bsum[blockIdx.x] = s[0];
}

// ---------------- scan stage 2: exclusive scan of block sums ----------------
// if tail != nullptr, writes tail[0] = tail_val (used for rowstart[N]=E)
__global__ void k_scan2(const int* __restrict__ bsum, int* __restrict__ boff,
                        int* __restrict__ tail, int tail_val) {
    __shared__ int s[512];
    int v = (threadIdx.x < NBLK) ? bsum[threadIdx.x] : 0;
    s[threadIdx.x] = v;
    __syncthreads();
    for (int off = 1; off < 512; off <<= 1) {
        int t = (threadIdx.x >= off) ? s[threadIdx.x - off] : 0;
        __syncthreads();
        s[threadIdx.x] += t;
        __syncthreads();
    }
    if (threadIdx.x < NBLK) boff[threadIdx.x] = s[threadIdx.x] - v;  // exclusive
    if (threadIdx.x == 0 && tail) tail[0] = tail_val;
}

// ---------------- scan stage 3 (deg): rowstart/cursor + fused dinv ----------
__global__ void k_scan3(const int* __restrict__ deg, const int* __restrict__ boff,
                        int* __restrict__ rowstart, int* __restrict__ cursor,
                        float* __restrict__ dinv) {
    __shared__ int s[SCAN_B];
    int i = blockIdx.x * SCAN_B + threadIdx.x;
    int v = (i < N_NODES) ? deg[i] : 0;
    s[threadIdx.x] = v;
    __syncthreads();
    for (int off = 1; off < SCAN_B; off <<= 1) {
        int t = (threadIdx.x >= off) ? s[threadIdx.x - off] : 0;
        __syncthreads();
        s[threadIdx.x] += t;
        __syncthreads();
    }
    if (i < N_NODES) {
        int ex = s[threadIdx.x] - v + boff[blockIdx.x];
        rowstart[i] = ex;
        cursor[i] = ex;
        dinv[i] = (v > 0) ? rsqrtf((float)v) : 0.0f;
    }
}

// ---------------- scan stage 3b (fB): mapB = compact slot or -1 -------------
__global__ void k_scan3b(const unsigned char* __restrict__ fB, const int* __restrict__ boff,
                         int* __restrict__ mapB) {
    __shared__ int s[SCAN_B];
    int i = blockIdx.x * SCAN_B + threadIdx.x;
    int v = (i < N_NODES) ? (int)fB[i] : 0;
    s[threadIdx.x] = v;
    __syncthreads();
    for (int off = 1; off < SCAN_B; off <<= 1) {
        int t = (threadIdx.x >= off) ? s[threadIdx.x - off] : 0;
        __syncthreads();
        s[threadIdx.x] += t;
        __syncthreads();
    }
    if (i < N_NODES) {
        int ex = s[threadIdx.x] - v + boff[blockIdx.x];
        mapB[i] = v ? ex : -1;
    }
}

// ---------------- scatter edges into CSR order ------------------------------
__global__ void k_scatter(const int* __restrict__ src, const int* __restrict__ dst,
                          int* __restrict__ cursor, int* __restrict__ csr_src) {
    int e = blockIdx.x * blockDim.x + threadIdx.x;
    if (e < N_EDGES) {
        int t = dst[e];
        int slot = atomicAdd(&cursor[t], 1);
        csr_src[slot] = src[e];
    }
}

// ---------------- mark batch indices into three byte flags ------------------
__global__ void k_mark(const int* __restrict__ u, const int* __restrict__ p,
                       const int* __restrict__ n, unsigned char* __restrict__ f3,
                       unsigned char* __restrict__ fA, unsigned char* __restrict__ fB) {
    int i = blockIdx.x * blockDim.x + threadIdx.x;
    if (i >= 3 * BATCH) return;
    int idx;
    if (i < BATCH)          idx = u[i];
    else if (i < 2 * BATCH) idx = p[i - BATCH];
    else                    idx = n[i - 2 * BATCH];
    f3[idx] = 1; fA[idx] = 1; fB[idx] = 1;
}

// ---------------- per-edge frontier expand: fout |= N_in(fin) ---------------
__global__ void k_expand_edges(const int* __restrict__ src, const int* __restrict__ dst,
                               const unsigned char* __restrict__ fin,
                               unsigned char* __restrict__ fout) {
    int e = blockIdx.x * blockDim.x + threadIdx.x;
    if (e < N_EDGES) {
        if (fin[dst[e]]) fout[src[e]] = 1;
    }
}

// ---------------- layer 1: emb -> x1c (compact, fB nodes) -------------------
__global__ void k_prop1(const float* __restrict__ emb, const int* __restrict__ mapB,
                        const float* __restrict__ dinv, const int* __restrict__ rowstart,
                        const int* __restrict__ csr_src, float* __restrict__ x1c) {
    int lane = threadIdx.x & 63;
    int w = (blockIdx.x * blockDim.x + threadIdx.x) >> 6;
    if (w >= N_NODES) return;
    int slot = mapB[w];
    if (slot < 0) return;
    float acc = 0.0f;
    int b = rowstart[w], e = rowstart[w + 1];
    for (int i = b; i < e; ++i) {
        int s = csr_src[i];
        acc += emb[(size_t)s * DIM + lane] * dinv[s];
    }
    x1c[(size_t)slot * DIM + lane] = acc * dinv[w];
}

// ---------------- layer 2: x1c -> x2 (full rows at fA nodes) ----------------
__global__ void k_prop2(const float* __restrict__ x1c, const int* __restrict__ mapB,
                        const unsigned char* __restrict__ fA,
                        const float* __restrict__ dinv, const int* __restrict__ rowstart,
                        const int* __restrict__ csr_src, float* __restrict__ x2) {
    int lane = threadIdx.x & 63;
    int w = (blockIdx.x * blockDim.x + threadIdx.x) >> 6;
    if (w >= N_NODES) return;
    if (!fA[w]) return;
    float acc = 0.0f;
    int b = rowstart[w], e = rowstart[w + 1];
    for (int i = b; i < e; ++i) {
        int s = csr_src[i];
        acc += x1c[(size_t)mapB[s] * DIM + lane] * dinv[s];
    }
    x2[(size_t)w * DIM + lane] = acc * dinv[w];
}

// ---------------- layer 3: x2 -> x3c (compact, 3*BATCH rows) ----------------
__global__ void k_prop3(const float* __restrict__ x2,
                        const int* __restrict__ u, const int* __restrict__ p,
                        const int* __restrict__ n,
                        const float* __restrict__ dinv, const int* __restrict__ rowstart,
                        const int* __restrict__ csr_src, float* __restrict__ x3c) {
    int lane = threadIdx.x & 63;
    int w = (blockIdx.x * blockDim.x + threadIdx.x) >> 6;
    if (w >= 3 * BATCH) return;
    int t;
    if (w < BATCH)          t = u[w];
    else if (w < 2 * BATCH) t = p[w - BATCH];
    else                    t = n[w - 2 * BATCH];
    float acc = 0.0f;
    int b = rowstart[t], e = rowstart[t + 1];
    for (int i = b; i < e; ++i) {
        int s = csr_src[i];
        acc += x2[(size_t)s * DIM + lane] * dinv[s];
    }
    x3c[(size_t)w * DIM + lane] = acc * dinv[t];
}

// ---------------- final loss ------------------------------------------------
__global__ void k_loss(const float* __restrict__ emb, const float* __restrict__ x1c,
                       const float* __restrict__ x2, const float* __restrict__ x3c,
                       const int* __restrict__ mapB,
                       const int* __restrict__ u, const int* __restrict__ p,
                       const int* __restrict__ n, float* __restrict__ out) {
    int lane = threadIdx.x & 63;
    int w = (blockIdx.x * blockDim.x + threadIdx.x) >> 6;
    if (w >= BATCH) return;
    int ui = u[w], pi = p[w], ni = n[w];
    float ue = emb[(size_t)ui * DIM + lane];
    float pe = emb[(size_t)pi * DIM + lane];
    float ne = emb[(size_t)ni * DIM + lane];
    float uall = 0.25f * (ue + x1c[(size_t)mapB[ui] * DIM + lane]
                             + x2[(size_t)ui * DIM + lane]
                             + x3c[(size_t)w * DIM + lane]);
    float pall = 0.25f * (pe + x1c[(size_t)mapB[pi] * DIM + lane]
                             + x2[(size_t)pi * DIM + lane]
                             + x3c[(size_t)(BATCH + w) * DIM + lane]);
    float nall = 0.25f * (ne + x1c[(size_t)mapB[ni] * DIM + lane]
                             + x2[(size_t)ni * DIM + lane]
                             + x3c[(size_t)(2 * BATCH + w) * DIM + lane]);
    float pos = uall * pall;
    float neg = uall * nall;
    float sq  = ue * ue + pe * pe + ne * ne;
    for (int off = 32; off; off >>= 1) {
        pos += __shfl_xor(pos, off, 64);
        neg += __shfl_xor(neg, off, 64);
        sq  += __shfl_xor(sq,  off, 64);
    }
    if (lane == 0) {
        float z = neg - pos;
        float sp = fmaxf(z, 0.0f) + log1pf(expf(-fabsf(z)));
        float contrib = sp * (1.0f / BATCH) + 1e-4f * 0.5f * sq * (1.0f / BATCH);
        atomicAdd(out, contrib);
    }
}

extern "C" void kernel_launch(void* const* d_in, const int* in_sizes, int n_in,
                              void* d_out, int out_size, void* d_ws, size_t ws_size,
                              hipStream_t stream) {
    const float* emb  = (const float*)d_in[0];
    const int*   edge = (const int*)d_in[1];
    const int*   src  = edge;
    const int*   dst  = edge + N_EDGES;
    const int*   uidx = (const int*)d_in[2];
    const int*   pidx = (const int*)d_in[3];
    const int*   nidx = (const int*)d_in[4];
    float* out = (float*)d_out;

    // ---- workspace layout (~240 MB total) ----
    char* w = (char*)d_ws;
    float* x2       = (float*)w;                 w += (size_t)N_NODES * DIM * 4;   // 128.0 MB
    float* x1c      = (float*)w;                 w += (size_t)X1C_CAP * DIM * 4;   //  89.6 MB
    float* x3c      = (float*)w;                 w += (size_t)3 * BATCH * DIM * 4; //   3.1 MB
    float* dinv     = (float*)w;                 w += (size_t)N_NODES * 4;
    int*   deg      = (int*)w;                   w += (size_t)N_NODES * 4;
    int*   rowstart = (int*)w;                   w += (size_t)(N_NODES + 4) * 4;
    int*   cursor   = (int*)w;                   w += (size_t)N_NODES * 4;
    int*   csr_src  = (int*)w;                   w += (size_t)N_EDGES * 4;
    int*   mapB     = (int*)w;                   w += (size_t)N_NODES * 4;
    unsigned char* f3 = (unsigned char*)w;       w += N_NODES;
    unsigned char* fA = (unsigned char*)w;       w += N_NODES;
    unsigned char* fB = (unsigned char*)w;       w += N_NODES;
    int*   bsum     = (int*)w;                   w += (size_t)NBLK * 4;
    int*   boff     = (int*)w;                   w += (size_t)NBLK * 4;
    int*   bsum2    = (int*)w;                   w += (size_t)NBLK * 4;
    int*   boff2    = (int*)w;                   w += (size_t)NBLK * 4;

    hipMemsetAsync(deg, 0, (size_t)N_NODES * 4, stream);
    hipMemsetAsync(f3, 0, N_NODES, stream);
    hipMemsetAsync(fA, 0, N_NODES, stream);
    hipMemsetAsync(fB, 0, N_NODES, stream);
    hipMemsetAsync(out, 0, 4, stream);

    // batch marks (independent of CSR)
    k_mark<<<(3 * BATCH + 255) / 256, 256, 0, stream>>>(uidx, pidx, nidx, f3, fA, fB);

    // CSR build (deg -> scan -> scatter), dinv fused into scan3
    k_deg<<<(N_EDGES + 255) / 256, 256, 0, stream>>>(dst, deg);
    k_scan1<<<NBLK, SCAN_B, 0, stream>>>(deg, bsum);
    k_scan2<<<1, 512, 0, stream>>>(bsum, boff, rowstart + N_NODES, N_EDGES);
    k_scan3<<<NBLK, SCAN_B, 0, stream>>>(deg, boff, rowstart, cursor, dinv);
    k_scatter<<<(N_EDGES + 255) / 256, 256, 0, stream>>>(src, dst, cursor, csr_src);

    // frontier expansion, per-edge (no atomics, no serial loops)
    k_expand_edges<<<(N_EDGES + 255) / 256, 256, 0, stream>>>(src, dst, f3, fA);
    k_expand_edges<<<(N_EDGES + 255) / 256, 256, 0, stream>>>(src, dst, fA, fB);

    // deterministic compact map via scan over fB
    k_scan1b<<<NBLK, SCAN_B, 0, stream>>>(fB, bsum2);
    k_scan2<<<1, 512, 0, stream>>>(bsum2, boff2, (int*)nullptr, 0);
    k_scan3b<<<NBLK, SCAN_B, 0, stream>>>(fB, boff2, mapB);

    // sparse propagation (pull-style over CSR, no float atomics)
    const int PROP_T = 256;
    k_prop1<<<((size_t)N_NODES * 64 + PROP_T - 1) / PROP_T, PROP_T, 0, stream>>>(
        emb, mapB, dinv, rowstart, csr_src, x1c);
    k_prop2<<<((size_t)N_NODES * 64 + PROP_T - 1) / PROP_T, PROP_T, 0, stream>>>(
        x1c, mapB, fA, dinv, rowstart, csr_src, x2);
    k_prop3<<<(3 * BATCH * 64 + PROP_T - 1) / PROP_T, PROP_T, 0, stream>>>(
        x2, uidx, pidx, nidx, dinv, rowstart, csr_src, x3c);

    k_loss<<<(BATCH * 64 + 255) / 256, 256, 0, stream>>>(
        emb, x1c, x2, x3c, mapB, uidx, pidx, nidx, out);
}

// Round 4
// 642.894 us; speedup vs baseline: 2.6863x; 1.2082x over previous
//
#include <hip/hip_runtime.h>
#include <cstdint>
#include <cstddef>

#define N_USERS   100000
#define N_NODES   500000
#define DIM       64
#define N_EDGES   2000000
#define BATCH     4096
#define SCAN_B    1024
#define NBLK      ((N_NODES + SCAN_B - 1) / SCAN_B)   // 489
#define X1C_CAP   350000   // compact x1 rows; |fB| ~220k measured-safe
#define LA_CAP    150000   // fA worklist cap; |fA| ~60k expected

// ---------------- degree histogram (int4-vectorized) ------------------------
__global__ void k_deg(const int* __restrict__ dst, int* __restrict__ deg) {
    int t = blockIdx.x * blockDim.x + threadIdx.x;
    if (t < N_EDGES / 4) {
        int4 d = ((const int4*)dst)[t];
        atomicAdd(&deg[d.x], 1); atomicAdd(&deg[d.y], 1);
        atomicAdd(&deg[d.z], 1); atomicAdd(&deg[d.w], 1);
    }
}

// ---------------- scan stage 1: per-block sums (deg) ------------------------
__global__ void k_scan1(const int* __restrict__ v, int* __restrict__ bsum) {
    __shared__ int s[SCAN_B];
    int i = blockIdx.x * SCAN_B + threadIdx.x;
    s[threadIdx.x] = (i < N_NODES) ? v[i] : 0;
    __syncthreads();
    for (int off = SCAN_B / 2; off; off >>= 1) {
        if (threadIdx.x < off) s[threadIdx.x] += s[threadIdx.x + off];
        __syncthreads();
    }
    if (threadIdx.x == 0) bsum[blockIdx.x] = s[0];
}

// ---------------- scan stage 2: exclusive scan of block sums (deg) ----------
__global__ void k_scan2(const int* __restrict__ bsum, int* __restrict__ boff,
                        int* __restrict__ tail, int tail_val) {
    __shared__ int s[512];
    int v = (threadIdx.x < NBLK) ? bsum[threadIdx.x] : 0;
    s[threadIdx.x] = v;
    __syncthreads();
    for (int off = 1; off < 512; off <<= 1) {
        int t = (threadIdx.x >= off) ? s[threadIdx.x - off] : 0;
        __syncthreads();
        s[threadIdx.x] += t;
        __syncthreads();
    }
    if (threadIdx.x < NBLK) boff[threadIdx.x] = s[threadIdx.x] - v;
    if (threadIdx.x == 0 && tail) tail[0] = tail_val;
}

// ---------------- scan stage 3 (deg): rowstart/cursor + fused dinv ----------
__global__ void k_scan3(const int* __restrict__ deg, const int* __restrict__ boff,
                        int* __restrict__ rowstart, int* __restrict__ cursor,
                        float* __restrict__ dinv) {
    __shared__ int s[SCAN_B];
    int i = blockIdx.x * SCAN_B + threadIdx.x;
    int v = (i < N_NODES) ? deg[i] : 0;
    s[threadIdx.x] = v;
    __syncthreads();
    for (int off = 1; off < SCAN_B; off <<= 1) {
        int t = (threadIdx.x >= off) ? s[threadIdx.x - off] : 0;
        __syncthreads();
        s[threadIdx.x] += t;
        __syncthreads();
    }
    if (i < N_NODES) {
        int ex = s[threadIdx.x] - v + boff[blockIdx.x];
        rowstart[i] = ex;
        cursor[i] = ex;
        dinv[i] = (v > 0) ? rsqrtf((float)v) : 0.0f;
    }
}

// ---------------- combined flag scan (fA, fB packed 16+16) ------------------
__global__ void k_scan1f(const unsigned char* __restrict__ fA,
                         const unsigned char* __restrict__ fB,
                         int* __restrict__ bsumP) {
    __shared__ int s[SCAN_B];
    int i = blockIdx.x * SCAN_B + threadIdx.x;
    int v = 0;
    if (i < N_NODES) v = (int)fA[i] | ((int)fB[i] << 16);
    s[threadIdx.x] = v;
    __syncthreads();
    for (int off = SCAN_B / 2; off; off >>= 1) {
        if (threadIdx.x < off) s[threadIdx.x] += s[threadIdx.x + off];
        __syncthreads();
    }
    if (threadIdx.x == 0) bsumP[blockIdx.x] = s[0];
}

__global__ void k_scan2f(const int* __restrict__ bsumP, int* __restrict__ boffA,
                         int* __restrict__ boffB, int* __restrict__ counts) {
    __shared__ int sA[512];
    __shared__ int sB[512];
    int p = (threadIdx.x < NBLK) ? bsumP[threadIdx.x] : 0;
    int vA = p & 0xFFFF, vB = p >> 16;
    sA[threadIdx.x] = vA; sB[threadIdx.x] = vB;
    __syncthreads();
    for (int off = 1; off < 512; off <<= 1) {
        int tA = (threadIdx.x >= off) ? sA[threadIdx.x - off] : 0;
        int tB = (threadIdx.x >= off) ? sB[threadIdx.x - off] : 0;
        __syncthreads();
        sA[threadIdx.x] += tA; sB[threadIdx.x] += tB;
        __syncthreads();
    }
    if (threadIdx.x < NBLK) {
        boffA[threadIdx.x] = sA[threadIdx.x] - vA;
        boffB[threadIdx.x] = sB[threadIdx.x] - vB;
    }
    if (threadIdx.x == 511) { counts[0] = sA[511]; counts[1] = sB[511]; }
}

__global__ void k_scan3f(const unsigned char* __restrict__ fA,
                         const unsigned char* __restrict__ fB,
                         const int* __restrict__ boffA, const int* __restrict__ boffB,
                         int* __restrict__ mapB, int* __restrict__ listA,
                         int* __restrict__ listB) {
    __shared__ int s[SCAN_B];
    int i = blockIdx.x * SCAN_B + threadIdx.x;
    int a = 0, b = 0;
    if (i < N_NODES) { a = (int)fA[i]; b = (int)fB[i]; }
    int v = a | (b << 16);
    s[threadIdx.x] = v;
    __syncthreads();
    for (int off = 1; off < SCAN_B; off <<= 1) {
        int t = (threadIdx.x >= off) ? s[threadIdx.x - off] : 0;
        __syncthreads();
        s[threadIdx.x] += t;
        __syncthreads();
    }
    if (i < N_NODES) {
        int inc = s[threadIdx.x];
        int exA = (inc & 0xFFFF) - a + boffA[blockIdx.x];
        int exB = (inc >> 16) - b + boffB[blockIdx.x];
        if (a) listA[exA] = i;
        mapB[i] = b ? exB : -1;
        if (b) listB[exB] = i;
    }
}

// ---------------- scatter edges into CSR order (int4-vectorized) ------------
__global__ void k_scatter(const int* __restrict__ src, const int* __restrict__ dst,
                          int* __restrict__ cursor, int* __restrict__ csr_src) {
    int t = blockIdx.x * blockDim.x + threadIdx.x;
    if (t < N_EDGES / 4) {
        int4 s = ((const int4*)src)[t];
        int4 d = ((const int4*)dst)[t];
        csr_src[atomicAdd(&cursor[d.x], 1)] = s.x;
        csr_src[atomicAdd(&cursor[d.y], 1)] = s.y;
        csr_src[atomicAdd(&cursor[d.z], 1)] = s.z;
        csr_src[atomicAdd(&cursor[d.w], 1)] = s.w;
    }
}

// ---------------- mark batch indices into three byte flags ------------------
__global__ void k_mark(const int* __restrict__ u, const int* __restrict__ p,
                       const int* __restrict__ n, unsigned char* __restrict__ f3,
                       unsigned char* __restrict__ fA, unsigned char* __restrict__ fB) {
    int i = blockIdx.x * blockDim.x + threadIdx.x;
    if (i >= 3 * BATCH) return;
    int idx;
    if (i < BATCH)          idx = u[i];
    else if (i < 2 * BATCH) idx = p[i - BATCH];
    else                    idx = n[i - 2 * BATCH];
    f3[idx] = 1; fA[idx] = 1; fB[idx] = 1;
}

// ---------------- per-edge frontier expand (int4-vectorized) ----------------
__global__ void k_expand_edges(const int* __restrict__ src, const int* __restrict__ dst,
                               const unsigned char* __restrict__ fin,
                               unsigned char* __restrict__ fout) {
    int t = blockIdx.x * blockDim.x + threadIdx.x;
    if (t < N_EDGES / 4) {
        int4 s = ((const int4*)src)[t];
        int4 d = ((const int4*)dst)[t];
        if (fin[d.x]) fout[s.x] = 1;
        if (fin[d.y]) fout[s.y] = 1;
        if (fin[d.z]) fout[s.z] = 1;
        if (fin[d.w]) fout[s.w] = 1;
    }
}

// ---------------- layer 1: emb -> x1c (compact, listB worklist) -------------
// wave per node; 4 sub-groups of 16 lanes gather 4 source rows concurrently
__global__ void k_prop1(const float* __restrict__ emb, const int* __restrict__ listB,
                        const int* __restrict__ counts,
                        const float* __restrict__ dinv, const int* __restrict__ rowstart,
                        const int* __restrict__ csr_src, float* __restrict__ x1c) {
    int lane = threadIdx.x & 63;
    int wv = (blockIdx.x * blockDim.x + threadIdx.x) >> 6;
    if (wv >= counts[1]) return;
    int node = listB[wv];
    int sub = lane >> 4, q = lane & 15;
    int b = rowstart[node], e = rowstart[node + 1];
    float4 acc = {0.f, 0.f, 0.f, 0.f};
    for (int i = b + sub; i < e; i += 4) {
        int s = csr_src[i];
        float dv = dinv[s];
        float4 v = ((const float4*)(emb + (size_t)s * DIM))[q];
        acc.x += v.x * dv; acc.y += v.y * dv; acc.z += v.z * dv; acc.w += v.w * dv;
    }
    for (int off = 16; off <= 32; off <<= 1) {
        acc.x += __shfl_xor(acc.x, off, 64);
        acc.y += __shfl_xor(acc.y, off, 64);
        acc.z += __shfl_xor(acc.z, off, 64);
        acc.w += __shfl_xor(acc.w, off, 64);
    }
    if (sub == 0) {
        float dw = dinv[node];
        float4 o = {acc.x * dw, acc.y * dw, acc.z * dw, acc.w * dw};
        ((float4*)x1c)[(size_t)wv * 16 + q] = o;
    }
}

// ---------------- layer 2: x1c -> x2 (listA worklist) -----------------------
__global__ void k_prop2(const float* __restrict__ x1c, const int* __restrict__ mapB,
                        const int* __restrict__ listA, const int* __restrict__ counts,
                        const float* __restrict__ dinv, const int* __restrict__ rowstart,
                        const int* __restrict__ csr_src, float* __restrict__ x2) {
    int lane = threadIdx.x & 63;
    int wv = (blockIdx.x * blockDim.x + threadIdx.x) >> 6;
    if (wv >= counts[0]) return;
    int node = listA[wv];
    int sub = lane >> 4, q = lane & 15;
    int b = rowstart[node], e = rowstart[node + 1];
    float4 acc = {0.f, 0.f, 0.f, 0.f};
    for (int i = b + sub; i < e; i += 4) {
        int s = csr_src[i];
        float dv = dinv[s];
        float4 v = ((const float4*)(x1c + (size_t)mapB[s] * DIM))[q];
        acc.x += v.x * dv; acc.y += v.y * dv; acc.z += v.z * dv; acc.w += v.w * dv;
    }
    for (int off = 16; off <= 32; off <<= 1) {
        acc.x += __shfl_xor(acc.x, off, 64);
        acc.y += __shfl_xor(acc.y, off, 64);
        acc.z += __shfl_xor(acc.z, off, 64);
        acc.w += __shfl_xor(acc.w, off, 64);
    }
    if (sub == 0) {
        float dw = dinv[node];
        float4 o = {acc.x * dw, acc.y * dw, acc.z * dw, acc.w * dw};
        ((float4*)(x2 + (size_t)node * DIM))[q] = o;
    }
}

// ---------------- layer 3: x2 -> x3c (compact, 3*BATCH rows) ----------------
__global__ void k_prop3(const float* __restrict__ x2,
                        const int* __restrict__ u, const int* __restrict__ p,
                        const int* __restrict__ n,
                        const float* __restrict__ dinv, const int* __restrict__ rowstart,
                        const int* __restrict__ csr_src, float* __restrict__ x3c) {
    int lane = threadIdx.x & 63;
    int wv = (blockIdx.x * blockDim.x + threadIdx.x) >> 6;
    if (wv >= 3 * BATCH) return;
    int t;
    if (wv < BATCH)          t = u[wv];
    else if (wv < 2 * BATCH) t = p[wv - BATCH];
    else                     t = n[wv - 2 * BATCH];
    int sub = lane >> 4, q = lane & 15;
    int b = rowstart[t], e = rowstart[t + 1];
    float4 acc = {0.f, 0.f, 0.f, 0.f};
    for (int i = b + sub; i < e; i += 4) {
        int s = csr_src[i];
        float dv = dinv[s];
        float4 v = ((const float4*)(x2 + (size_t)s * DIM))[q];
        acc.x += v.x * dv; acc.y += v.y * dv; acc.z += v.z * dv; acc.w += v.w * dv;
    }
    for (int off = 16; off <= 32; off <<= 1) {
        acc.x += __shfl_xor(acc.x, off, 64);
        acc.y += __shfl_xor(acc.y, off, 64);
        acc.z += __shfl_xor(acc.z, off, 64);
        acc.w += __shfl_xor(acc.w, off, 64);
    }
    if (sub == 0) {
        float dw = dinv[t];
        float4 o = {acc.x * dw, acc.y * dw, acc.z * dw, acc.w * dw};
        ((float4*)x3c)[(size_t)wv * 16 + q] = o;
    }
}

// ---------------- final loss ------------------------------------------------
__global__ void k_loss(const float* __restrict__ emb, const float* __restrict__ x1c,
                       const float* __restrict__ x2, const float* __restrict__ x3c,
                       const int* __restrict__ mapB,
                       const int* __restrict__ u, const int* __restrict__ p,
                       const int* __restrict__ n, float* __restrict__ out) {
    int lane = threadIdx.x & 63;
    int w = (blockIdx.x * blockDim.x + threadIdx.x) >> 6;
    if (w >= BATCH) return;
    int ui = u[w], pi = p[w], ni = n[w];
    float ue = emb[(size_t)ui * DIM + lane];
    float pe = emb[(size_t)pi * DIM + lane];
    float ne = emb[(size_t)ni * DIM + lane];
    float uall = 0.25f * (ue + x1c[(size_t)mapB[ui] * DIM + lane]
                             + x2[(size_t)ui * DIM + lane]
                             + x3c[(size_t)w * DIM + lane]);
    float pall = 0.25f * (pe + x1c[(size_t)mapB[pi] * DIM + lane]
                             + x2[(size_t)pi * DIM + lane]
                             + x3c[(size_t)(BATCH + w) * DIM + lane]);
    float nall = 0.25f * (ne + x1c[(size_t)mapB[ni] * DIM + lane]
                             + x2[(size_t)ni * DIM + lane]
                             + x3c[(size_t)(2 * BATCH + w) * DIM + lane]);
    float pos = uall * pall;
    float neg = uall * nall;
    float sq  = ue * ue + pe * pe + ne * ne;
    for (int off = 32; off; off >>= 1) {
        pos += __shfl_xor(pos, off, 64);
        neg += __shfl_xor(neg, off, 64);
        sq  += __shfl_xor(sq,  off, 64);
    }
    if (lane == 0) {
        float z = neg - pos;
        float sp = fmaxf(z, 0.0f) + log1pf(expf(-fabsf(z)));
        float contrib = sp * (1.0f / BATCH) + 1e-4f * 0.5f * sq * (1.0f / BATCH);
        atomicAdd(out, contrib);
    }
}

extern "C" void kernel_launch(void* const* d_in, const int* in_sizes, int n_in,
                              void* d_out, int out_size, void* d_ws, size_t ws_size,
                              hipStream_t stream) {
    const float* emb  = (const float*)d_in[0];
    const int*   edge = (const int*)d_in[1];
    const int*   src  = edge;
    const int*   dst  = edge + N_EDGES;
    const int*   uidx = (const int*)d_in[2];
    const int*   pidx = (const int*)d_in[3];
    const int*   nidx = (const int*)d_in[4];
    float* out = (float*)d_out;

    // ---- workspace layout (~245 MB total) ----
    char* w = (char*)d_ws;
    float* x2       = (float*)w;                 w += (size_t)N_NODES * DIM * 4;   // 128.0 MB
    float* x1c      = (float*)w;                 w += (size_t)X1C_CAP * DIM * 4;   //  89.6 MB
    float* x3c      = (float*)w;                 w += (size_t)3 * BATCH * DIM * 4; //   3.1 MB
    float* dinv     = (float*)w;                 w += (size_t)N_NODES * 4;
    int*   deg      = (int*)w;                   w += (size_t)N_NODES * 4;
    int*   rowstart = (int*)w;                   w += (size_t)(N_NODES + 4) * 4;
    int*   cursor   = (int*)w;                   w += (size_t)N_NODES * 4;
    int*   csr_src  = (int*)w;                   w += (size_t)N_EDGES * 4;
    int*   mapB     = (int*)w;                   w += (size_t)N_NODES * 4;
    int*   listB    = (int*)w;                   w += (size_t)X1C_CAP * 4;
    int*   listA    = (int*)w;                   w += (size_t)LA_CAP * 4;
    unsigned char* flags = (unsigned char*)w;    w += (size_t)3 * N_NODES;  // f3|fA|fB contiguous
    unsigned char* f3 = flags;
    unsigned char* fA = flags + N_NODES;
    unsigned char* fB = flags + 2 * N_NODES;
    int*   bsum     = (int*)w;                   w += (size_t)NBLK * 4;
    int*   boff     = (int*)w;                   w += (size_t)NBLK * 4;
    int*   bsumP    = (int*)w;                   w += (size_t)NBLK * 4;
    int*   boffA    = (int*)w;                   w += (size_t)NBLK * 4;
    int*   boffB    = (int*)w;                   w += (size_t)NBLK * 4;
    int*   counts   = (int*)w;                   w += 16;   // [0]=|fA|, [1]=|fB|

    hipMemsetAsync(deg, 0, (size_t)N_NODES * 4, stream);
    hipMemsetAsync(flags, 0, (size_t)3 * N_NODES, stream);
    hipMemsetAsync(out, 0, 4, stream);

    // batch marks (independent of CSR)
    k_mark<<<(3 * BATCH + 255) / 256, 256, 0, stream>>>(uidx, pidx, nidx, f3, fA, fB);

    // CSR build (deg -> scan -> scatter), dinv fused into scan3
    k_deg<<<(N_EDGES / 4 + 255) / 256, 256, 0, stream>>>(dst, deg);
    k_scan1<<<NBLK, SCAN_B, 0, stream>>>(deg, bsum);
    k_scan2<<<1, 512, 0, stream>>>(bsum, boff, rowstart + N_NODES, N_EDGES);
    k_scan3<<<NBLK, SCAN_B, 0, stream>>>(deg, boff, rowstart, cursor, dinv);
    k_scatter<<<(N_EDGES / 4 + 255) / 256, 256, 0, stream>>>(src, dst, cursor, csr_src);

    // frontier expansion, per-edge
    k_expand_edges<<<(N_EDGES / 4 + 255) / 256, 256, 0, stream>>>(src, dst, f3, fA);
    k_expand_edges<<<(N_EDGES / 4 + 255) / 256, 256, 0, stream>>>(src, dst, fA, fB);

    // combined compact maps/worklists via packed scan over fA,fB
    k_scan1f<<<NBLK, SCAN_B, 0, stream>>>(fA, fB, bsumP);
    k_scan2f<<<1, 512, 0, stream>>>(bsumP, boffA, boffB, counts);
    k_scan3f<<<NBLK, SCAN_B, 0, stream>>>(fA, fB, boffA, boffB, mapB, listA, listB);

    // sparse propagation (pull-style, worklist-driven, 4-edge-concurrent)
    const int PT = 256;
    k_prop1<<<((size_t)X1C_CAP * 64 + PT - 1) / PT, PT, 0, stream>>>(
        emb, listB, counts, dinv, rowstart, csr_src, x1c);
    k_prop2<<<((size_t)LA_CAP * 64 + PT - 1) / PT, PT, 0, stream>>>(
        x1c, mapB, listA, counts, dinv, rowstart, csr_src, x2);
    k_prop3<<<(3 * BATCH * 64 + PT - 1) / PT, PT, 0, stream>>>(
        x2, uidx, pidx, nidx, dinv, rowstart, csr_src, x3c);

    k_loss<<<(BATCH * 64 + 255) / 256, 256, 0, stream>>>(
        emb, x1c, x2, x3c, mapB, uidx, pidx, nidx, out);
}

// Round 5
// 529.461 us; speedup vs baseline: 3.2618x; 1.2142x over previous
//
#include <hip/hip_runtime.h>
#include <cstdint>
#include <cstddef>

#define N_USERS   100000
#define N_NODES   500000
#define DIM       64
#define N_EDGES   2000000
#define BATCH     4096
#define SCAN_B    1024
#define NBLK      ((N_NODES + SCAN_B - 1) / SCAN_B)   // 489
#define X1C_CAP   350000   // compact x1 rows; |fB| ~222k measured-safe
#define LA_CAP    150000   // fA worklist cap; |fA| ~60k expected

// ---------------- degree histogram (int4-vectorized) ------------------------
__global__ void k_deg(const int* __restrict__ dst, int* __restrict__ deg) {
    int t = blockIdx.x * blockDim.x + threadIdx.x;
    if (t < N_EDGES / 4) {
        int4 d = ((const int4*)dst)[t];
        atomicAdd(&deg[d.x], 1); atomicAdd(&deg[d.y], 1);
        atomicAdd(&deg[d.z], 1); atomicAdd(&deg[d.w], 1);
    }
}

// ---------------- scan stage 1: per-block sums (deg) ------------------------
__global__ void k_scan1(const int* __restrict__ v, int* __restrict__ bsum) {
    __shared__ int s[SCAN_B];
    int i = blockIdx.x * SCAN_B + threadIdx.x;
    s[threadIdx.x] = (i < N_NODES) ? v[i] : 0;
    __syncthreads();
    for (int off = SCAN_B / 2; off; off >>= 1) {
        if (threadIdx.x < off) s[threadIdx.x] += s[threadIdx.x + off];
        __syncthreads();
    }
    if (threadIdx.x == 0) bsum[blockIdx.x] = s[0];
}

// ---------------- scan stage 2: exclusive scan of block sums (deg) ----------
__global__ void k_scan2(const int* __restrict__ bsum, int* __restrict__ boff,
                        int* __restrict__ tail, int tail_val) {
    __shared__ int s[512];
    int v = (threadIdx.x < NBLK) ? bsum[threadIdx.x] : 0;
    s[threadIdx.x] = v;
    __syncthreads();
    for (int off = 1; off < 512; off <<= 1) {
        int t = (threadIdx.x >= off) ? s[threadIdx.x - off] : 0;
        __syncthreads();
        s[threadIdx.x] += t;
        __syncthreads();
    }
    if (threadIdx.x < NBLK) boff[threadIdx.x] = s[threadIdx.x] - v;
    if (threadIdx.x == 0 && tail) tail[0] = tail_val;
}

// ---------------- scan stage 3 (deg): rowstart/cursor + fused dinv ----------
__global__ void k_scan3(const int* __restrict__ deg, const int* __restrict__ boff,
                        int* __restrict__ rowstart, int* __restrict__ cursor,
                        float* __restrict__ dinv) {
    __shared__ int s[SCAN_B];
    int i = blockIdx.x * SCAN_B + threadIdx.x;
    int v = (i < N_NODES) ? deg[i] : 0;
    s[threadIdx.x] = v;
    __syncthreads();
    for (int off = 1; off < SCAN_B; off <<= 1) {
        int t = (threadIdx.x >= off) ? s[threadIdx.x - off] : 0;
        __syncthreads();
        s[threadIdx.x] += t;
        __syncthreads();
    }
    if (i < N_NODES) {
        int ex = s[threadIdx.x] - v + boff[blockIdx.x];
        rowstart[i] = ex;
        cursor[i] = ex;
        dinv[i] = (v > 0) ? rsqrtf((float)v) : 0.0f;
    }
}

// ---------------- combined flag scan (fA, fB packed 16+16) ------------------
__global__ void k_scan1f(const unsigned char* __restrict__ fA,
                         const unsigned char* __restrict__ fB,
                         int* __restrict__ bsumP) {
    __shared__ int s[SCAN_B];
    int i = blockIdx.x * SCAN_B + threadIdx.x;
    int v = 0;
    if (i < N_NODES) v = (int)fA[i] | ((int)fB[i] << 16);
    s[threadIdx.x] = v;
    __syncthreads();
    for (int off = SCAN_B / 2; off; off >>= 1) {
        if (threadIdx.x < off) s[threadIdx.x] += s[threadIdx.x + off];
        __syncthreads();
    }
    if (threadIdx.x == 0) bsumP[blockIdx.x] = s[0];
}

__global__ void k_scan2f(const int* __restrict__ bsumP, int* __restrict__ boffA,
                         int* __restrict__ boffB, int* __restrict__ counts) {
    __shared__ int sA[512];
    __shared__ int sB[512];
    int p = (threadIdx.x < NBLK) ? bsumP[threadIdx.x] : 0;
    int vA = p & 0xFFFF, vB = p >> 16;
    sA[threadIdx.x] = vA; sB[threadIdx.x] = vB;
    __syncthreads();
    for (int off = 1; off < 512; off <<= 1) {
        int tA = (threadIdx.x >= off) ? sA[threadIdx.x - off] : 0;
        int tB = (threadIdx.x >= off) ? sB[threadIdx.x - off] : 0;
        __syncthreads();
        sA[threadIdx.x] += tA; sB[threadIdx.x] += tB;
        __syncthreads();
    }
    if (threadIdx.x < NBLK) {
        boffA[threadIdx.x] = sA[threadIdx.x] - vA;
        boffB[threadIdx.x] = sB[threadIdx.x] - vB;
    }
    if (threadIdx.x == 511) { counts[0] = sA[511]; counts[1] = sB[511]; }
}

__global__ void k_scan3f(const unsigned char* __restrict__ fA,
                         const unsigned char* __restrict__ fB,
                         const int* __restrict__ boffA, const int* __restrict__ boffB,
                         int* __restrict__ mapB, int* __restrict__ listA,
                         int* __restrict__ listB) {
    __shared__ int s[SCAN_B];
    int i = blockIdx.x * SCAN_B + threadIdx.x;
    int a = 0, b = 0;
    if (i < N_NODES) { a = (int)fA[i]; b = (int)fB[i]; }
    int v = a | (b << 16);
    s[threadIdx.x] = v;
    __syncthreads();
    for (int off = 1; off < SCAN_B; off <<= 1) {
        int t = (threadIdx.x >= off) ? s[threadIdx.x - off] : 0;
        __syncthreads();
        s[threadIdx.x] += t;
        __syncthreads();
    }
    if (i < N_NODES) {
        int inc = s[threadIdx.x];
        int exA = (inc & 0xFFFF) - a + boffA[blockIdx.x];
        int exB = (inc >> 16) - b + boffB[blockIdx.x];
        if (a) listA[exA] = i;
        mapB[i] = b ? exB : -1;
        if (b) listB[exB] = i;
    }
}

// ---------------- masked scatter: only edges whose dst is in fB -------------
__global__ void k_scatter(const int* __restrict__ src, const int* __restrict__ dst,
                          const unsigned char* __restrict__ fB,
                          int* __restrict__ cursor, int* __restrict__ csr_src) {
    int t = blockIdx.x * blockDim.x + threadIdx.x;
    if (t < N_EDGES / 4) {
        int4 s = ((const int4*)src)[t];
        int4 d = ((const int4*)dst)[t];
        if (fB[d.x]) csr_src[atomicAdd(&cursor[d.x], 1)] = s.x;
        if (fB[d.y]) csr_src[atomicAdd(&cursor[d.y], 1)] = s.y;
        if (fB[d.z]) csr_src[atomicAdd(&cursor[d.z], 1)] = s.z;
        if (fB[d.w]) csr_src[atomicAdd(&cursor[d.w], 1)] = s.w;
    }
}

// ---------------- mark batch indices into three byte flags ------------------
__global__ void k_mark(const int* __restrict__ u, const int* __restrict__ p,
                       const int* __restrict__ n, unsigned char* __restrict__ f3,
                       unsigned char* __restrict__ fA, unsigned char* __restrict__ fB) {
    int i = blockIdx.x * blockDim.x + threadIdx.x;
    if (i >= 3 * BATCH) return;
    int idx;
    if (i < BATCH)          idx = u[i];
    else if (i < 2 * BATCH) idx = p[i - BATCH];
    else                    idx = n[i - 2 * BATCH];
    f3[idx] = 1; fA[idx] = 1; fB[idx] = 1;
}

// ---------------- per-edge frontier expand, write-dedup ---------------------
__global__ void k_expand_edges(const int* __restrict__ src, const int* __restrict__ dst,
                               const unsigned char* __restrict__ fin,
                               unsigned char* __restrict__ fout) {
    int t = blockIdx.x * blockDim.x + threadIdx.x;
    if (t < N_EDGES / 4) {
        int4 s = ((const int4*)src)[t];
        int4 d = ((const int4*)dst)[t];
        if (fin[d.x] && !fout[s.x]) fout[s.x] = 1;
        if (fin[d.y] && !fout[s.y]) fout[s.y] = 1;
        if (fin[d.z] && !fout[s.z]) fout[s.z] = 1;
        if (fin[d.w] && !fout[s.w]) fout[s.w] = 1;
    }
}

// ---------------- layer 1: emb -> x1c (compact, listB worklist) -------------
__global__ void k_prop1(const float* __restrict__ emb, const int* __restrict__ listB,
                        const int* __restrict__ counts,
                        const float* __restrict__ dinv, const int* __restrict__ rowstart,
                        const int* __restrict__ csr_src, float* __restrict__ x1c) {
    int lane = threadIdx.x & 63;
    int wv = (blockIdx.x * blockDim.x + threadIdx.x) >> 6;
    if (wv >= counts[1]) return;
    int node = listB[wv];
    int sub = lane >> 4, q = lane & 15;
    int b = rowstart[node], e = rowstart[node + 1];
    float4 acc = {0.f, 0.f, 0.f, 0.f};
    for (int i = b + sub; i < e; i += 4) {
        int s = csr_src[i];
        float dv = dinv[s];
        float4 v = ((const float4*)(emb + (size_t)s * DIM))[q];
        acc.x += v.x * dv; acc.y += v.y * dv; acc.z += v.z * dv; acc.w += v.w * dv;
    }
    for (int off = 16; off <= 32; off <<= 1) {
        acc.x += __shfl_xor(acc.x, off, 64);
        acc.y += __shfl_xor(acc.y, off, 64);
        acc.z += __shfl_xor(acc.z, off, 64);
        acc.w += __shfl_xor(acc.w, off, 64);
    }
    if (sub == 0) {
        float dw = dinv[node];
        float4 o = {acc.x * dw, acc.y * dw, acc.z * dw, acc.w * dw};
        ((float4*)x1c)[(size_t)wv * 16 + q] = o;
    }
}

// ---------------- layer 2: x1c -> x2 (listA worklist) -----------------------
__global__ void k_prop2(const float* __restrict__ x1c, const int* __restrict__ mapB,
                        const int* __restrict__ listA, const int* __restrict__ counts,
                        const float* __restrict__ dinv, const int* __restrict__ rowstart,
                        const int* __restrict__ csr_src, float* __restrict__ x2) {
    int lane = threadIdx.x & 63;
    int wv = (blockIdx.x * blockDim.x + threadIdx.x) >> 6;
    if (wv >= counts[0]) return;
    int node = listA[wv];
    int sub = lane >> 4, q = lane & 15;
    int b = rowstart[node], e = rowstart[node + 1];
    float4 acc = {0.f, 0.f, 0.f, 0.f};
    for (int i = b + sub; i < e; i += 4) {
        int s = csr_src[i];
        float dv = dinv[s];
        float4 v = ((const float4*)(x1c + (size_t)mapB[s] * DIM))[q];
        acc.x += v.x * dv; acc.y += v.y * dv; acc.z += v.z * dv; acc.w += v.w * dv;
    }
    for (int off = 16; off <= 32; off <<= 1) {
        acc.x += __shfl_xor(acc.x, off, 64);
        acc.y += __shfl_xor(acc.y, off, 64);
        acc.z += __shfl_xor(acc.z, off, 64);
        acc.w += __shfl_xor(acc.w, off, 64);
    }
    if (sub == 0) {
        float dw = dinv[node];
        float4 o = {acc.x * dw, acc.y * dw, acc.z * dw, acc.w * dw};
        ((float4*)(x2 + (size_t)node * DIM))[q] = o;
    }
}

// ---------------- layer 3: x2 -> x3c (compact, 3*BATCH rows) ----------------
__global__ void k_prop3(const float* __restrict__ x2,
                        const int* __restrict__ u, const int* __restrict__ p,
                        const int* __restrict__ n,
                        const float* __restrict__ dinv, const int* __restrict__ rowstart,
                        const int* __restrict__ csr_src, float* __restrict__ x3c) {
    int lane = threadIdx.x & 63;
    int wv = (blockIdx.x * blockDim.x + threadIdx.x) >> 6;
    if (wv >= 3 * BATCH) return;
    int t;
    if (wv < BATCH)          t = u[wv];
    else if (wv < 2 * BATCH) t = p[wv - BATCH];
    else                     t = n[wv - 2 * BATCH];
    int sub = lane >> 4, q = lane & 15;
    int b = rowstart[t], e = rowstart[t + 1];
    float4 acc = {0.f, 0.f, 0.f, 0.f};
    for (int i = b + sub; i < e; i += 4) {
        int s = csr_src[i];
        float dv = dinv[s];
        float4 v = ((const float4*)(x2 + (size_t)s * DIM))[q];
        acc.x += v.x * dv; acc.y += v.y * dv; acc.z += v.z * dv; acc.w += v.w * dv;
    }
    for (int off = 16; off <= 32; off <<= 1) {
        acc.x += __shfl_xor(acc.x, off, 64);
        acc.y += __shfl_xor(acc.y, off, 64);
        acc.z += __shfl_xor(acc.z, off, 64);
        acc.w += __shfl_xor(acc.w, off, 64);
    }
    if (sub == 0) {
        float dw = dinv[t];
        float4 o = {acc.x * dw, acc.y * dw, acc.z * dw, acc.w * dw};
        ((float4*)x3c)[(size_t)wv * 16 + q] = o;
    }
}

// ---------------- final loss ------------------------------------------------
__global__ void k_loss(const float* __restrict__ emb, const float* __restrict__ x1c,
                       const float* __restrict__ x2, const float* __restrict__ x3c,
                       const int* __restrict__ mapB,
                       const int* __restrict__ u, const int* __restrict__ p,
                       const int* __restrict__ n, float* __restrict__ out) {
    int lane = threadIdx.x & 63;
    int w = (blockIdx.x * blockDim.x + threadIdx.x) >> 6;
    if (w >= BATCH) return;
    int ui = u[w], pi = p[w], ni = n[w];
    float ue = emb[(size_t)ui * DIM + lane];
    float pe = emb[(size_t)pi * DIM + lane];
    float ne = emb[(size_t)ni * DIM + lane];
    float uall = 0.25f * (ue + x1c[(size_t)mapB[ui] * DIM + lane]
                             + x2[(size_t)ui * DIM + lane]
                             + x3c[(size_t)w * DIM + lane]);
    float pall = 0.25f * (pe + x1c[(size_t)mapB[pi] * DIM + lane]
                             + x2[(size_t)pi * DIM + lane]
                             + x3c[(size_t)(BATCH + w) * DIM + lane]);
    float nall = 0.25f * (ne + x1c[(size_t)mapB[ni] * DIM + lane]
                             + x2[(size_t)ni * DIM + lane]
                             + x3c[(size_t)(2 * BATCH + w) * DIM + lane]);
    float pos = uall * pall;
    float neg = uall * nall;
    float sq  = ue * ue + pe * pe + ne * ne;
    for (int off = 32; off; off >>= 1) {
        pos += __shfl_xor(pos, off, 64);
        neg += __shfl_xor(neg, off, 64);
        sq  += __shfl_xor(sq,  off, 64);
    }
    if (lane == 0) {
        float z = neg - pos;
        float sp = fmaxf(z, 0.0f) + log1pf(expf(-fabsf(z)));
        float contrib = sp * (1.0f / BATCH) + 1e-4f * 0.5f * sq * (1.0f / BATCH);
        atomicAdd(out, contrib);
    }
}

extern "C" void kernel_launch(void* const* d_in, const int* in_sizes, int n_in,
                              void* d_out, int out_size, void* d_ws, size_t ws_size,
                              hipStream_t stream) {
    const float* emb  = (const float*)d_in[0];
    const int*   edge = (const int*)d_in[1];
    const int*   src  = edge;
    const int*   dst  = edge + N_EDGES;
    const int*   uidx = (const int*)d_in[2];
    const int*   pidx = (const int*)d_in[3];
    const int*   nidx = (const int*)d_in[4];
    float* out = (float*)d_out;

    // ---- workspace layout (~245 MB total) ----
    char* w = (char*)d_ws;
    float* x2       = (float*)w;                 w += (size_t)N_NODES * DIM * 4;   // 128.0 MB
    float* x1c      = (float*)w;                 w += (size_t)X1C_CAP * DIM * 4;   //  89.6 MB
    float* x3c      = (float*)w;                 w += (size_t)3 * BATCH * DIM * 4; //   3.1 MB
    float* dinv     = (float*)w;                 w += (size_t)N_NODES * 4;
    int*   deg      = (int*)w;                   w += (size_t)N_NODES * 4;
    int*   rowstart = (int*)w;                   w += (size_t)(N_NODES + 4) * 4;
    int*   cursor   = (int*)w;                   w += (size_t)N_NODES * 4;
    int*   csr_src  = (int*)w;                   w += (size_t)N_EDGES * 4;
    int*   mapB     = (int*)w;                   w += (size_t)N_NODES * 4;
    int*   listB    = (int*)w;                   w += (size_t)X1C_CAP * 4;
    int*   listA    = (int*)w;                   w += (size_t)LA_CAP * 4;
    unsigned char* flags = (unsigned char*)w;    w += (size_t)3 * N_NODES;  // f3|fA|fB contiguous
    unsigned char* f3 = flags;
    unsigned char* fA = flags + N_NODES;
    unsigned char* fB = flags + 2 * N_NODES;
    int*   bsum     = (int*)w;                   w += (size_t)NBLK * 4;
    int*   boff     = (int*)w;                   w += (size_t)NBLK * 4;
    int*   bsumP    = (int*)w;                   w += (size_t)NBLK * 4;
    int*   boffA    = (int*)w;                   w += (size_t)NBLK * 4;
    int*   boffB    = (int*)w;                   w += (size_t)NBLK * 4;
    int*   counts   = (int*)w;                   w += 16;   // [0]=|fA|, [1]=|fB|

    hipMemsetAsync(deg, 0, (size_t)N_NODES * 4, stream);
    hipMemsetAsync(flags, 0, (size_t)3 * N_NODES, stream);
    hipMemsetAsync(out, 0, 4, stream);

    // frontier construction first (needs only the raw edge list)
    k_mark<<<(3 * BATCH + 255) / 256, 256, 0, stream>>>(uidx, pidx, nidx, f3, fA, fB);
    k_expand_edges<<<(N_EDGES / 4 + 255) / 256, 256, 0, stream>>>(src, dst, f3, fA);
    k_expand_edges<<<(N_EDGES / 4 + 255) / 256, 256, 0, stream>>>(src, dst, fA, fB);

    // CSR build (deg -> scan -> masked scatter), dinv fused into scan3
    k_deg<<<(N_EDGES / 4 + 255) / 256, 256, 0, stream>>>(dst, deg);
    k_scan1<<<NBLK, SCAN_B, 0, stream>>>(deg, bsum);
    k_scan2<<<1, 512, 0, stream>>>(bsum, boff, rowstart + N_NODES, N_EDGES);
    k_scan3<<<NBLK, SCAN_B, 0, stream>>>(deg, boff, rowstart, cursor, dinv);
    k_scatter<<<(N_EDGES / 4 + 255) / 256, 256, 0, stream>>>(src, dst, fB, cursor, csr_src);

    // combined compact maps/worklists via packed scan over fA,fB
    k_scan1f<<<NBLK, SCAN_B, 0, stream>>>(fA, fB, bsumP);
    k_scan2f<<<1, 512, 0, stream>>>(bsumP, boffA, boffB, counts);
    k_scan3f<<<NBLK, SCAN_B, 0, stream>>>(fA, fB, boffA, boffB, mapB, listA, listB);

    // sparse propagation (pull-style, worklist-driven, 4-edge-concurrent)
    const int PT = 256;
    k_prop1<<<((size_t)X1C_CAP * 64 + PT - 1) / PT, PT, 0, stream>>>(
        emb, listB, counts, dinv, rowstart, csr_src, x1c);
    k_prop2<<<((size_t)LA_CAP * 64 + PT - 1) / PT, PT, 0, stream>>>(
        x1c, mapB, listA, counts, dinv, rowstart, csr_src, x2);
    k_prop3<<<(3 * BATCH * 64 + PT - 1) / PT, PT, 0, stream>>>(
        x2, uidx, pidx, nidx, dinv, rowstart, csr_src, x3c);

    k_loss<<<(BATCH * 64 + 255) / 256, 256, 0, stream>>>(
        emb, x1c, x2, x3c, mapB, uidx, pidx, nidx, out);
}

// Round 6
// 501.911 us; speedup vs baseline: 3.4409x; 1.0549x over previous
//
#include <hip/hip_runtime.h>
#include <cstdint>
#include <cstddef>

#define N_USERS   100000
#define N_NODES   500000
#define DIM       64
#define N_EDGES   2000000
#define BATCH     4096
#define SCAN_B    1024
#define NBLK      ((N_NODES + SCAN_B - 1) / SCAN_B)   // 489
#define X1C_CAP   350000   // |fB| ~230k measured-safe
#define LA_CAP    150000   // |fA| ~60k expected

typedef unsigned char uchar;
typedef unsigned short ushort;
typedef unsigned int uint;

__device__ __forceinline__ ushort f2bf(float f) {
    uint u = __float_as_uint(f);
    uint r = u + 0x7FFFu + ((u >> 16) & 1u);
    return (ushort)(r >> 16);
}
__device__ __forceinline__ float bflo(uint u) { return __uint_as_float(u << 16); }
__device__ __forceinline__ float bfhi(uint u) { return __uint_as_float(u & 0xFFFF0000u); }

// ---------- fused: degree histogram + expand f3 -> fA (one edge pass) -------
__global__ void k_degexp(const int* __restrict__ src, const int* __restrict__ dst,
                         int* __restrict__ deg, const uchar* __restrict__ f3,
                         uchar* __restrict__ fA) {
    int t = blockIdx.x * blockDim.x + threadIdx.x;
    if (t < N_EDGES / 4) {
        int4 s = ((const int4*)src)[t];
        int4 d = ((const int4*)dst)[t];
        atomicAdd(&deg[d.x], 1); atomicAdd(&deg[d.y], 1);
        atomicAdd(&deg[d.z], 1); atomicAdd(&deg[d.w], 1);
        if (f3[d.x] && !fA[s.x]) fA[s.x] = 1;
        if (f3[d.y] && !fA[s.y]) fA[s.y] = 1;
        if (f3[d.z] && !fA[s.z]) fA[s.z] = 1;
        if (f3[d.w] && !fA[s.w]) fA[s.w] = 1;
    }
}

// ---------- expand fA -> fB (dedup writes) ----------------------------------
__global__ void k_expand(const int* __restrict__ src, const int* __restrict__ dst,
                         const uchar* __restrict__ fin, uchar* __restrict__ fout) {
    int t = blockIdx.x * blockDim.x + threadIdx.x;
    if (t < N_EDGES / 4) {
        int4 s = ((const int4*)src)[t];
        int4 d = ((const int4*)dst)[t];
        if (fin[d.x] && !fout[s.x]) fout[s.x] = 1;
        if (fin[d.y] && !fout[s.y]) fout[s.y] = 1;
        if (fin[d.z] && !fout[s.z]) fout[s.z] = 1;
        if (fin[d.w] && !fout[s.w]) fout[s.w] = 1;
    }
}

// ---------- mark batch indices into three byte flags ------------------------
__global__ void k_mark(const int* __restrict__ u, const int* __restrict__ p,
                       const int* __restrict__ n, uchar* __restrict__ f3,
                       uchar* __restrict__ fA, uchar* __restrict__ fB) {
    int i = blockIdx.x * blockDim.x + threadIdx.x;
    if (i >= 3 * BATCH) return;
    int idx;
    if (i < BATCH)          idx = u[i];
    else if (i < 2 * BATCH) idx = p[i - BATCH];
    else                    idx = n[i - 2 * BATCH];
    f3[idx] = 1; fA[idx] = 1; fB[idx] = 1;
}

// ---------- scan A: per-block sums of deg (int) and fA|fB (packed) ----------
__global__ void k_scanA(const int* __restrict__ deg, const uchar* __restrict__ fA,
                        const uchar* __restrict__ fB, int* __restrict__ bsumD,
                        int* __restrict__ bsumP) {
    __shared__ int sD[SCAN_B];
    __shared__ int sP[SCAN_B];
    int i = blockIdx.x * SCAN_B + threadIdx.x;
    int d = 0, pk = 0;
    if (i < N_NODES) { d = deg[i]; pk = (int)fA[i] | ((int)fB[i] << 16); }
    sD[threadIdx.x] = d; sP[threadIdx.x] = pk;
    __syncthreads();
    for (int off = SCAN_B / 2; off; off >>= 1) {
        if (threadIdx.x < off) {
            sD[threadIdx.x] += sD[threadIdx.x + off];
            sP[threadIdx.x] += sP[threadIdx.x + off];
        }
        __syncthreads();
    }
    if (threadIdx.x == 0) { bsumD[blockIdx.x] = sD[0]; bsumP[blockIdx.x] = sP[0]; }
}

// ---------- scan B: exclusive scans of block sums ---------------------------
__global__ void k_scanB(const int* __restrict__ bsumD, const int* __restrict__ bsumP,
                        int* __restrict__ boffD, int* __restrict__ boffA,
                        int* __restrict__ boffB, int* __restrict__ counts,
                        int* __restrict__ rowstart_tail) {
    __shared__ int sD[512];
    __shared__ int sA[512];
    __shared__ int sB[512];
    int d = (threadIdx.x < NBLK) ? bsumD[threadIdx.x] : 0;
    int p = (threadIdx.x < NBLK) ? bsumP[threadIdx.x] : 0;
    int a = p & 0xFFFF, b = p >> 16;
    sD[threadIdx.x] = d; sA[threadIdx.x] = a; sB[threadIdx.x] = b;
    __syncthreads();
    for (int off = 1; off < 512; off <<= 1) {
        int tD = (threadIdx.x >= off) ? sD[threadIdx.x - off] : 0;
        int tA = (threadIdx.x >= off) ? sA[threadIdx.x - off] : 0;
        int tB = (threadIdx.x >= off) ? sB[threadIdx.x - off] : 0;
        __syncthreads();
        sD[threadIdx.x] += tD; sA[threadIdx.x] += tA; sB[threadIdx.x] += tB;
        __syncthreads();
    }
    if (threadIdx.x < NBLK) {
        boffD[threadIdx.x] = sD[threadIdx.x] - d;
        boffA[threadIdx.x] = sA[threadIdx.x] - a;
        boffB[threadIdx.x] = sB[threadIdx.x] - b;
    }
    if (threadIdx.x == 511) {
        counts[0] = sA[511]; counts[1] = sB[511];
        rowstart_tail[0] = N_EDGES;
    }
}

// ---------- scan C: rowstart/cursor/dinv + mapA/mapB + packed worklists -----
__global__ void k_scanC(const int* __restrict__ deg, const uchar* __restrict__ fA,
                        const uchar* __restrict__ fB,
                        const int* __restrict__ boffD, const int* __restrict__ boffA,
                        const int* __restrict__ boffB,
                        int* __restrict__ rowstart, int* __restrict__ cursor,
                        float* __restrict__ dinv, int* __restrict__ mapA,
                        int* __restrict__ mapB, int4* __restrict__ listA4,
                        int4* __restrict__ listB4) {
    __shared__ int sD[SCAN_B];
    __shared__ int sP[SCAN_B];
    int i = blockIdx.x * SCAN_B + threadIdx.x;
    int d = 0, a = 0, b = 0;
    if (i < N_NODES) { d = deg[i]; a = (int)fA[i]; b = (int)fB[i]; }
    sD[threadIdx.x] = d; sP[threadIdx.x] = a | (b << 16);
    __syncthreads();
    for (int off = 1; off < SCAN_B; off <<= 1) {
        int tD = (threadIdx.x >= off) ? sD[threadIdx.x - off] : 0;
        int tP = (threadIdx.x >= off) ? sP[threadIdx.x - off] : 0;
        __syncthreads();
        sD[threadIdx.x] += tD; sP[threadIdx.x] += tP;
        __syncthreads();
    }
    if (i < N_NODES) {
        int exD = sD[threadIdx.x] - d + boffD[blockIdx.x];
        int incP = sP[threadIdx.x];
        int exA = (incP & 0xFFFF) - a + boffA[blockIdx.x];
        int exB = (incP >> 16) - b + boffB[blockIdx.x];
        rowstart[i] = exD;
        cursor[i] = exD;
        float dv = (d > 0) ? rsqrtf((float)d) : 0.0f;
        dinv[i] = dv;
        mapA[i] = a ? exA : -1;
        mapB[i] = b ? exB : -1;
        int4 ent = make_int4(exD, exD + d, __float_as_int(dv), 0);
        if (a) listA4[exA] = ent;
        if (b) listB4[exB] = ent;
    }
}

// ---------- conv: embs = bf16(emb * dinv[row]) (pre-scaled) -----------------
__global__ void k_conv(const float* __restrict__ emb, const float* __restrict__ dinv,
                       ushort* __restrict__ embs) {
    int c = blockIdx.x * blockDim.x + threadIdx.x;   // chunk of 4 floats
    if (c < N_NODES * 16) {
        int row = c >> 4;
        float4 v = ((const float4*)emb)[c];
        float dv = dinv[row];
        uint2 o;
        o.x = (uint)f2bf(v.x * dv) | ((uint)f2bf(v.y * dv) << 16);
        o.y = (uint)f2bf(v.z * dv) | ((uint)f2bf(v.w * dv) << 16);
        ((uint2*)embs)[c] = o;
    }
}

// ---------- masked scatter: only edges whose dst is in fB -------------------
__global__ void k_scatter(const int* __restrict__ src, const int* __restrict__ dst,
                          const uchar* __restrict__ fB,
                          int* __restrict__ cursor, int* __restrict__ csr_src) {
    int t = blockIdx.x * blockDim.x + threadIdx.x;
    if (t < N_EDGES / 4) {
        int4 s = ((const int4*)src)[t];
        int4 d = ((const int4*)dst)[t];
        if (fB[d.x]) csr_src[atomicAdd(&cursor[d.x], 1)] = s.x;
        if (fB[d.y]) csr_src[atomicAdd(&cursor[d.y], 1)] = s.y;
        if (fB[d.z]) csr_src[atomicAdd(&cursor[d.z], 1)] = s.z;
        if (fB[d.w]) csr_src[atomicAdd(&cursor[d.w], 1)] = s.w;
    }
}

// ---------- layer 1: embs(bf16, pre-scaled) -> x1c(bf16, x1*dinv[node]) -----
__global__ void k_prop1(const ushort* __restrict__ embs, const int4* __restrict__ listB4,
                        const int* __restrict__ counts, const int* __restrict__ csr_src,
                        ushort* __restrict__ x1c) {
    int lane = threadIdx.x & 63;
    int wv = (blockIdx.x * blockDim.x + threadIdx.x) >> 6;
    if (wv >= counts[1]) return;
    int4 nb = listB4[wv];
    int sub = lane >> 4, q = lane & 15;
    float4 acc = {0.f, 0.f, 0.f, 0.f};
    for (int i = nb.x + sub; i < nb.y; i += 4) {
        int s = csr_src[i];
        uint2 u = *(const uint2*)(embs + (size_t)s * DIM + q * 4);
        acc.x += bflo(u.x); acc.y += bfhi(u.x);
        acc.z += bflo(u.y); acc.w += bfhi(u.y);
    }
    for (int off = 16; off <= 32; off <<= 1) {
        acc.x += __shfl_xor(acc.x, off, 64);
        acc.y += __shfl_xor(acc.y, off, 64);
        acc.z += __shfl_xor(acc.z, off, 64);
        acc.w += __shfl_xor(acc.w, off, 64);
    }
    if (sub == 0) {
        float dv = __int_as_float(nb.z);
        float d2 = dv * dv;   // store x1*dinv[node] for next layer
        uint2 o;
        o.x = (uint)f2bf(acc.x * d2) | ((uint)f2bf(acc.y * d2) << 16);
        o.y = (uint)f2bf(acc.z * d2) | ((uint)f2bf(acc.w * d2) << 16);
        *(uint2*)(x1c + (size_t)wv * DIM + q * 4) = o;
    }
}

// ---------- layer 2: x1c -> x2c (bf16, x2*dinv[node]) -----------------------
__global__ void k_prop2(const ushort* __restrict__ x1c, const int* __restrict__ mapB,
                        const int4* __restrict__ listA4, const int* __restrict__ counts,
                        const int* __restrict__ csr_src, ushort* __restrict__ x2c) {
    int lane = threadIdx.x & 63;
    int wv = (blockIdx.x * blockDim.x + threadIdx.x) >> 6;
    if (wv >= counts[0]) return;
    int4 nb = listA4[wv];
    int sub = lane >> 4, q = lane & 15;
    float4 acc = {0.f, 0.f, 0.f, 0.f};
    for (int i = nb.x + sub; i < nb.y; i += 4) {
        int s = csr_src[i];
        int slot = mapB[s];
        uint2 u = *(const uint2*)(x1c + (size_t)slot * DIM + q * 4);
        acc.x += bflo(u.x); acc.y += bfhi(u.x);
        acc.z += bflo(u.y); acc.w += bfhi(u.y);
    }
    for (int off = 16; off <= 32; off <<= 1) {
        acc.x += __shfl_xor(acc.x, off, 64);
        acc.y += __shfl_xor(acc.y, off, 64);
        acc.z += __shfl_xor(acc.z, off, 64);
        acc.w += __shfl_xor(acc.w, off, 64);
    }
    if (sub == 0) {
        float dv = __int_as_float(nb.z);
        float d2 = dv * dv;
        uint2 o;
        o.x = (uint)f2bf(acc.x * d2) | ((uint)f2bf(acc.y * d2) << 16);
        o.y = (uint)f2bf(acc.z * d2) | ((uint)f2bf(acc.w * d2) << 16);
        *(uint2*)(x2c + (size_t)wv * DIM + q * 4) = o;
    }
}

// ---------- layer 3: x2c -> x3c (fp32 true values, 3*BATCH rows) ------------
__global__ void k_prop3(const ushort* __restrict__ x2c, const int* __restrict__ mapA,
                        const int* __restrict__ u, const int* __restrict__ p,
                        const int* __restrict__ n, const float* __restrict__ dinv,
                        const int* __restrict__ rowstart, const int* __restrict__ csr_src,
                        float* __restrict__ x3c) {
    int lane = threadIdx.x & 63;
    int wv = (blockIdx.x * blockDim.x + threadIdx.x) >> 6;
    if (wv >= 3 * BATCH) return;
    int t;
    if (wv < BATCH)          t = u[wv];
    else if (wv < 2 * BATCH) t = p[wv - BATCH];
    else                     t = n[wv - 2 * BATCH];
    int sub = lane >> 4, q = lane & 15;
    int b = rowstart[t], e = rowstart[t + 1];
    float4 acc = {0.f, 0.f, 0.f, 0.f};
    for (int i = b + sub; i < e; i += 4) {
        int s = csr_src[i];
        int slot = mapA[s];
        uint2 uu = *(const uint2*)(x2c + (size_t)slot * DIM + q * 4);
        acc.x += bflo(uu.x); acc.y += bfhi(uu.x);
        acc.z += bflo(uu.y); acc.w += bfhi(uu.y);
    }
    for (int off = 16; off <= 32; off <<= 1) {
        acc.x += __shfl_xor(acc.x, off, 64);
        acc.y += __shfl_xor(acc.y, off, 64);
        acc.z += __shfl_xor(acc.z, off, 64);
        acc.w += __shfl_xor(acc.w, off, 64);
    }
    if (sub == 0) {
        float dv = dinv[t];
        float4 o = {acc.x * dv, acc.y * dv, acc.z * dv, acc.w * dv};
        ((float4*)x3c)[(size_t)wv * 16 + q] = o;
    }
}

// ---------- final loss ------------------------------------------------------
__global__ void k_loss(const float* __restrict__ emb, const ushort* __restrict__ x1c,
                       const ushort* __restrict__ x2c, const float* __restrict__ x3c,
                       const int* __restrict__ mapA, const int* __restrict__ mapB,
                       const float* __restrict__ dinv,
                       const int* __restrict__ u, const int* __restrict__ p,
                       const int* __restrict__ n, float* __restrict__ out) {
    int lane = threadIdx.x & 63;
    int w = (blockIdx.x * blockDim.x + threadIdx.x) >> 6;
    if (w >= BATCH) return;
    int ui = u[w], pi = p[w], ni = n[w];
    float dvu = dinv[ui], dvp = dinv[pi], dvn = dinv[ni];
    float rdu = dvu > 0.f ? 1.f / dvu : 0.f;
    float rdp = dvp > 0.f ? 1.f / dvp : 0.f;
    float rdn = dvn > 0.f ? 1.f / dvn : 0.f;
    float ue = emb[(size_t)ui * DIM + lane];
    float pe = emb[(size_t)pi * DIM + lane];
    float ne = emb[(size_t)ni * DIM + lane];
    float u1 = __uint_as_float((uint)x1c[(size_t)mapB[ui] * DIM + lane] << 16) * rdu;
    float p1 = __uint_as_float((uint)x1c[(size_t)mapB[pi] * DIM + lane] << 16) * rdp;
    float n1 = __uint_as_float((uint)x1c[(size_t)mapB[ni] * DIM + lane] << 16) * rdn;
    float u2 = __uint_as_float((uint)x2c[(size_t)mapA[ui] * DIM + lane] << 16) * rdu;
    float p2 = __uint_as_float((uint)x2c[(size_t)mapA[pi] * DIM + lane] << 16) * rdp;
    float n2 = __uint_as_float((uint)x2c[(size_t)mapA[ni] * DIM + lane] << 16) * rdn;
    float uall = 0.25f * (ue + u1 + u2 + x3c[(size_t)w * DIM + lane]);
    float pall = 0.25f * (pe + p1 + p2 + x3c[(size_t)(BATCH + w) * DIM + lane]);
    float nall = 0.25f * (ne + n1 + n2 + x3c[(size_t)(2 * BATCH + w) * DIM + lane]);
    float pos = uall * pall;
    float neg = uall * nall;
    float sq  = ue * ue + pe * pe + ne * ne;
    for (int off = 32; off; off >>= 1) {
        pos += __shfl_xor(pos, off, 64);
        neg += __shfl_xor(neg, off, 64);
        sq  += __shfl_xor(sq,  off, 64);
    }
    if (lane == 0) {
        float z = neg - pos;
        float sp = fmaxf(z, 0.0f) + log1pf(expf(-fabsf(z)));
        float contrib = sp * (1.0f / BATCH) + 1e-4f * 0.5f * sq * (1.0f / BATCH);
        atomicAdd(out, contrib);
    }
}

extern "C" void kernel_launch(void* const* d_in, const int* in_sizes, int n_in,
                              void* d_out, int out_size, void* d_ws, size_t ws_size,
                              hipStream_t stream) {
    const float* emb  = (const float*)d_in[0];
    const int*   edge = (const int*)d_in[1];
    const int*   src  = edge;
    const int*   dst  = edge + N_EDGES;
    const int*   uidx = (const int*)d_in[2];
    const int*   pidx = (const int*)d_in[3];
    const int*   nidx = (const int*)d_in[4];
    float* out = (float*)d_out;

    // ---- workspace layout (~160 MB) ----
    char* w = (char*)d_ws;
    ushort* embs    = (ushort*)w;                w += (size_t)N_NODES * DIM * 2;   // 64 MB
    ushort* x1c     = (ushort*)w;                w += (size_t)X1C_CAP * DIM * 2;   // 44.8 MB
    ushort* x2c     = (ushort*)w;                w += (size_t)LA_CAP * DIM * 2;    // 19.2 MB
    float*  x3c     = (float*)w;                 w += (size_t)3 * BATCH * DIM * 4; // 3.1 MB
    float*  dinv    = (float*)w;                 w += (size_t)N_NODES * 4;
    int*    deg     = (int*)w;                   w += (size_t)N_NODES * 4;
    int*    rowstart= (int*)w;                   w += (size_t)(N_NODES + 4) * 4;
    int*    cursor  = (int*)w;                   w += (size_t)N_NODES * 4;
    int*    csr_src = (int*)w;                   w += (size_t)N_EDGES * 4;
    int*    mapA    = (int*)w;                   w += (size_t)N_NODES * 4;
    int*    mapB    = (int*)w;                   w += (size_t)N_NODES * 4;
    int4*   listA4  = (int4*)w;                  w += (size_t)LA_CAP * 16;
    int4*   listB4  = (int4*)w;                  w += (size_t)X1C_CAP * 16;
    uchar*  flags   = (uchar*)w;                 w += (size_t)3 * N_NODES;
    uchar*  f3 = flags;
    uchar*  fA = flags + N_NODES;
    uchar*  fB = flags + 2 * N_NODES;
    int*    bsumD   = (int*)w;                   w += (size_t)NBLK * 4;
    int*    boffD   = (int*)w;                   w += (size_t)NBLK * 4;
    int*    bsumP   = (int*)w;                   w += (size_t)NBLK * 4;
    int*    boffA   = (int*)w;                   w += (size_t)NBLK * 4;
    int*    boffB   = (int*)w;                   w += (size_t)NBLK * 4;
    int*    counts  = (int*)w;                   w += 16;   // [0]=|fA|, [1]=|fB|

    hipMemsetAsync(deg, 0, (size_t)N_NODES * 4, stream);
    hipMemsetAsync(flags, 0, (size_t)3 * N_NODES, stream);
    hipMemsetAsync(out, 0, 4, stream);

    // frontier + degree (2 edge passes instead of 3)
    k_mark<<<(3 * BATCH + 255) / 256, 256, 0, stream>>>(uidx, pidx, nidx, f3, fA, fB);
    k_degexp<<<(N_EDGES / 4 + 255) / 256, 256, 0, stream>>>(src, dst, deg, f3, fA);
    k_expand<<<(N_EDGES / 4 + 255) / 256, 256, 0, stream>>>(src, dst, fA, fB);

    // fused scan trio: CSR offsets + dinv + compact maps + packed worklists
    k_scanA<<<NBLK, SCAN_B, 0, stream>>>(deg, fA, fB, bsumD, bsumP);
    k_scanB<<<1, 512, 0, stream>>>(bsumD, bsumP, boffD, boffA, boffB, counts,
                                   rowstart + N_NODES);
    k_scanC<<<NBLK, SCAN_B, 0, stream>>>(deg, fA, fB, boffD, boffA, boffB,
                                         rowstart, cursor, dinv, mapA, mapB,
                                         listA4, listB4);

    // bf16 pre-scaled staging of emb
    k_conv<<<(N_NODES * 16 + 255) / 256, 256, 0, stream>>>(emb, dinv, embs);

    // masked CSR fill
    k_scatter<<<(N_EDGES / 4 + 255) / 256, 256, 0, stream>>>(src, dst, fB, cursor, csr_src);

    // sparse propagation
    const int PT = 256;
    k_prop1<<<((size_t)X1C_CAP * 64 + PT - 1) / PT, PT, 0, stream>>>(
        embs, listB4, counts, csr_src, x1c);
    k_prop2<<<((size_t)LA_CAP * 64 + PT - 1) / PT, PT, 0, stream>>>(
        x1c, mapB, listA4, counts, csr_src, x2c);
    k_prop3<<<(3 * BATCH * 64 + PT - 1) / PT, PT, 0, stream>>>(
        x2c, mapA, uidx, pidx, nidx, dinv, rowstart, csr_src, x3c);

    k_loss<<<(BATCH * 64 + 255) / 256, 256, 0, stream>>>(
        emb, x1c, x2c, x3c, mapA, mapB, dinv, uidx, pidx, nidx, out);
}